// Round 12
// baseline (1016.705 us; speedup 1.0000x reference)
//
#include <hip/hip_runtime.h>
#include <math.h>

#define TOK_L 3073
#define EMB 768
#define NH 12
#define DH 64
#define BATCH 2
#define QKVS 2304
#define HSZ ((size_t)BATCH * TOK_L * EMB)   // 4,720,128
#define MHC ((size_t)BATCH * TOK_L * NH)    // 73,752

typedef __bf16 bf16;
typedef __bf16 v8bf __attribute__((ext_vector_type(8)));
typedef __bf16 v4bf __attribute__((ext_vector_type(4)));
typedef __bf16 v2bf __attribute__((ext_vector_type(2)));
typedef float  v4f  __attribute__((ext_vector_type(4)));
typedef unsigned int v4u __attribute__((ext_vector_type(4)));

__device__ __forceinline__ v8bf zero8() {
    v8bf v;
    #pragma unroll
    for (int i = 0; i < 8; i++) v[i] = (bf16)0.f;
    return v;
}
__device__ __forceinline__ v4f zero4() {
    v4f v; v[0] = 0.f; v[1] = 0.f; v[2] = 0.f; v[3] = 0.f; return v;
}
__device__ __forceinline__ float gelu_f(float x) {
    return 0.5f * x * (1.0f + erff(x * 0.70710678118654752f));
}
// async global->LDS, 16B per lane; lds base must be wave-uniform (lane scatters +lane*16B)
__device__ __forceinline__ void gload16(const bf16* g, bf16* l) {
    __builtin_amdgcn_global_load_lds(
        (const __attribute__((address_space(1))) void*)g,
        (__attribute__((address_space(3))) void*)l, 16, 0, 0);
}
// inline-asm ds_read_b128 (volatile: not CSE'd, invisible to alias-waitcnt pass;
// rule #18: consumers need explicit lgkmcnt(0)+sched_barrier).
__device__ __forceinline__ v8bf lds_read128(const bf16* p) {
    v8bf r;
    asm volatile("ds_read_b128 %0, %1"
        : "=v"(r)
        : "v"((const __attribute__((address_space(3))) bf16*)p));
    return r;
}

// ---------------------------------------------------------------------------
// Mega weight-prep: 12 transpose-converts + patch_w cvt. grid = 14592.
// ---------------------------------------------------------------------------
__device__ __forceinline__ void convT_tile(const float* __restrict__ src,
                                           bf16* __restrict__ dst,
                                           int K, int N, int tx, int ty)
{
    __shared__ float t[32][33];
    int n0 = tx * 32, k0 = ty * 32;
    int r = threadIdx.x >> 3, c4 = (threadIdx.x & 7) * 4;
    float4 v = *(const float4*)(src + (size_t)(k0 + r) * N + n0 + c4);
    t[r][c4 + 0] = v.x; t[r][c4 + 1] = v.y; t[r][c4 + 2] = v.z; t[r][c4 + 3] = v.w;
    __syncthreads();
    v4bf o;
    o[0] = (bf16)t[c4 + 0][r]; o[1] = (bf16)t[c4 + 1][r];
    o[2] = (bf16)t[c4 + 2][r]; o[3] = (bf16)t[c4 + 3][r];
    *(v4bf*)(dst + (size_t)(n0 + r) * K + k0 + c4) = o;
}

__global__ __launch_bounds__(256) void prep_weights(
    const float* __restrict__ wq, const float* __restrict__ wk,
    const float* __restrict__ wv, const float* __restrict__ wo,
    const float* __restrict__ w1, const float* __restrict__ w2,
    const float* __restrict__ patch_w,
    bf16* __restrict__ qkv_t0, bf16* __restrict__ wo_t0,
    bf16* __restrict__ w1_t, bf16* __restrict__ w2_t, bf16* __restrict__ pw_b)
{
    int bid = blockIdx.x;
    if (bid >= 13824) {
        int i = ((bid - 13824) * 256 + threadIdx.x) * 4;
        float4 v = *(const float4*)(patch_w + i);
        v4bf o; o[0] = (bf16)v.x; o[1] = (bf16)v.y; o[2] = (bf16)v.z; o[3] = (bf16)v.w;
        *(v4bf*)(pw_b + i) = o;
        return;
    }
    int layer = bid / 6912, t = bid % 6912;
    if (t < 1728) {
        int m = t / 576, tt = t % 576;
        const float* src = (m == 0 ? wq : m == 1 ? wk : wv) + (size_t)layer * 589824;
        bf16* dst = qkv_t0 + (size_t)layer * QKVS * 768 + (size_t)m * 589824;
        convT_tile(src, dst, 768, 768, tt % 24, tt / 24);
    } else if (t < 2304) {
        int tt = t - 1728;
        convT_tile(wo + (size_t)layer * 589824, wo_t0 + (size_t)layer * 589824,
                   768, 768, tt % 24, tt / 24);
    } else if (t < 4608) {
        int tt = t - 2304;
        convT_tile(w1 + (size_t)layer * 2359296, w1_t + (size_t)layer * 2359296,
                   768, 3072, tt % 96, tt / 96);
    } else {
        int tt = t - 4608;
        convT_tile(w2 + (size_t)layer * 2359296, w2_t + (size_t)layer * 2359296,
                   3072, 768, tt % 24, tt / 24);
    }
}

// concat q/k/v biases -> bqkv[layer][2304]; also init cls rows of h. grid 18.
__global__ __launch_bounds__(256) void prep_small(const float* __restrict__ bq,
    const float* __restrict__ bk, const float* __restrict__ bv, float* __restrict__ d,
    const float* __restrict__ cls, const float* __restrict__ pos, float* __restrict__ h)
{
    int i = blockIdx.x * 256 + threadIdx.x;
    if (i < 2 * QKVS) {
        int layer = i / QKVS, j = i % QKVS;
        const float* s = (j < 768) ? bq : (j < 1536) ? bk : bv;
        d[i] = s[(size_t)layer * 768 + (j & 767)];
    }
    if (i < 2 * 768) {
        int b = i / 768, e = i % 768;
        h[(size_t)b * TOK_L * EMB + e] = cls[e] + pos[e];
    }
}

// ---------------------------------------------------------------------------
// Patch gather: x (B,1,48,256,256) fp32 -> Xp (B*3072, 1024) bf16.
// ---------------------------------------------------------------------------
__global__ __launch_bounds__(256) void gather_patches(const float* __restrict__ x,
                                                      bf16* __restrict__ Xp) {
    int p = blockIdx.x;
    int b = p / 3072, pp = p % 3072;
    int px = pp >> 8, py = (pp >> 4) & 15, pz = pp & 15;
    int k = threadIdx.x * 4;                 // pw 4-aligned, contiguous quad
    int pd = k >> 8, ph = (k >> 4) & 15, pw = k & 15;
    size_t src = ((size_t)(b * 48 + px * 4 + pd)) * 65536
               + (size_t)(py * 16 + ph) * 256 + (size_t)(pz * 16 + pw);
    float4 v = *(const float4*)(x + src);
    v4bf o; o[0] = (bf16)v.x; o[1] = (bf16)v.y; o[2] = (bf16)v.z; o[3] = (bf16)v.w;
    *(v4bf*)(Xp + (size_t)p * 1024 + k) = o;
}

// ---------------------------------------------------------------------------
// XCD-chunked, panel-grouped tile remap (bijective, m204-style 8-way split).
// ---------------------------------------------------------------------------
__device__ __forceinline__ void remap_tile(int NX, int MY, int G, int& xo, int& yo)
{
    int id = blockIdx.x + NX * blockIdx.y;   // physical linear id
    int nwg = NX * MY;
    int xcd = id & 7, j = id >> 3;           // physical XCD + slot (id%8 = XCD)
    int q = nwg >> 3, r = nwg & 7;
    int n = xcd * q + (xcd < r ? xcd : r) + j;   // logical rank (bijective)
    int full = MY / G;
    int bpg = NX * G;
    int nf = full * bpg;
    if (n < nf) {
        int gi = n / bpg, w = n - gi * bpg;
        int xi = w / G;
        xo = xi; yo = gi * G + (w - xi * G);
    } else {
        int t = MY - full * G;               // tail rows (>0 iff taken)
        int w = n - nf;
        int xi = w / t;
        xo = xi; yo = full * G + (w - xi * t);
    }
}

// ---------------------------------------------------------------------------
// 256x256 8-phase GEMM, template-faithful port (3rd attempt; root cause of
// prior 107us: all 24 fragment v8bf read in ph0/ph1 and held live across 4
// phases (96 VGPR liveness vs 128-reg cap) -> regalloc collapse. Fix: per-
// phase reads, consumed immediately (12 ds_read + 16 MFMA per phase, ~48
// transient regs), exactly the m201 discipline).
// Geometry: 512 thr = 8 waves (2M x 4N), BK=64, per-wave out 128x64. Each
// wave's strip lies in ONE A-half / ONE B-half (slot idx R>>7 / C>>7 is
// wave-fixed). 4-slot rings: tile j reads slots (2j)&3,(2j+1)&3; stages for
// tile j+1 write (2j+2)&3,(2j+3)&3 -> DISJOINT (WAR-safe by construction;
// prev occupants retired at tile j-1's last barrier). Stage stream per tile:
// ph0 A(j+1,h0) [+vmcnt(2): completes exactly tile j's 8 loads, ledger
// verified], ph1 A(j+1,h1), ph2 B(j+1,h0), ph3 B(j+1,h1). XOR swizzle
// (chunk ^= row&7) via pre-swizzled global source + swizzled asm ds_read
// (bank-conflict-free, measured 0). N%256==0 required.
// ---------------------------------------------------------------------------
__global__ __launch_bounds__(512, 2) void gemm256(
    const bf16* __restrict__ A, const bf16* __restrict__ Bt,
    const float* __restrict__ bias, bf16* __restrict__ Cb,
    int M, int N, int K, int dogelu, int G)
{
    __shared__ bf16 AB[65536];               // A slots [0,32768), B slots [32768,65536)
    const int tid = threadIdx.x;
    const int lane = tid & 63, wid = tid >> 6;
    const int ln15 = lane & 15, q4 = lane >> 4;
    int xo, yo;
    remap_tile(gridDim.x, gridDim.y, G, xo, yo);
    const int m0 = yo * 256, n0 = xo * 256;
    const int wm = (wid & 1) * 128, wn = (wid >> 1) * 64;
    const int srow = wid * 8 + (lane >> 3);                       // + i*64 (+ h*128)
    const int schunk = ((lane & 7) ^ ((lane >> 3) & 7)) * 8;      // pre-swizzled src
    const int NT = K >> 6;

    auto stageA = [&](int t, int h) {
        const int slot = (2 * t + h) & 3;
        bf16* dstb = AB + slot * 8192 + wid * 512;
        const int k0 = t << 6;
        #pragma unroll
        for (int i = 0; i < 2; i++) {
            int gm = m0 + h * 128 + i * 64 + srow; if (gm >= M) gm = M - 1;
            gload16(A + (size_t)gm * K + k0 + schunk, dstb + i * 4096);
        }
    };
    auto stageB = [&](int t, int h) {
        const int slot = (2 * t + h) & 3;
        bf16* dstb = AB + 32768 + slot * 8192 + wid * 512;
        const int k0 = t << 6;
        #pragma unroll
        for (int i = 0; i < 2; i++) {
            int gn = n0 + h * 128 + i * 64 + srow;
            gload16(Bt + (size_t)gn * K + k0 + schunk, dstb + i * 4096);
        }
    };
    auto rdA = [&](int kt, int mt, int ks) -> v8bf {
        int R = wm + mt * 16 + ln15;
        int slot = (2 * kt + (R >> 7)) & 3;
        int r7 = R & 127;
        return lds_read128(AB + slot * 8192 + r7 * 64 + ((ks * 4 + q4) ^ (r7 & 7)) * 8);
    };
    auto rdB = [&](int kt, int nt, int ks) -> v8bf {
        int C = wn + nt * 16 + ln15;
        int slot = (2 * kt + (C >> 7)) & 3;
        int c7 = C & 127;
        return lds_read128(AB + 32768 + slot * 8192 + c7 * 64 + ((ks * 4 + q4) ^ (c7 & 7)) * 8);
    };

    v4f acc[8][4];
    #pragma unroll
    for (int i = 0; i < 8; i++)
        #pragma unroll
        for (int j = 0; j < 4; j++) acc[i][j] = zero4();

    // prologue: tile 0 (8 loads)
    stageA(0, 0); stageA(0, 1); stageB(0, 0); stageB(0, 1);

    for (int kt = 0; kt < NT; kt++) {
        // ---------------- ph0: quadrant (mt 0-3, nt 0-1)
        if (kt + 1 < NT) {
            stageA(kt + 1, 0);
            asm volatile("s_waitcnt vmcnt(2)" ::: "memory");   // tile kt fully landed
        } else {
            asm volatile("s_waitcnt vmcnt(0)" ::: "memory");
        }
        __builtin_amdgcn_sched_barrier(0);
        __builtin_amdgcn_s_barrier();
        __builtin_amdgcn_sched_barrier(0);
        {
            v8bf af[4][2], bfr[2][2];
            #pragma unroll
            for (int mt = 0; mt < 4; mt++) { af[mt][0] = rdA(kt, mt, 0); af[mt][1] = rdA(kt, mt, 1); }
            #pragma unroll
            for (int nt = 0; nt < 2; nt++) { bfr[nt][0] = rdB(kt, nt, 0); bfr[nt][1] = rdB(kt, nt, 1); }
            asm volatile("s_waitcnt lgkmcnt(0)" ::: "memory");
            __builtin_amdgcn_sched_barrier(0);
            __builtin_amdgcn_s_setprio(1);
            #pragma unroll
            for (int mt = 0; mt < 4; mt++)
                #pragma unroll
                for (int nt = 0; nt < 2; nt++)
                    #pragma unroll
                    for (int ks = 0; ks < 2; ks++)
                        acc[mt][nt] = __builtin_amdgcn_mfma_f32_16x16x32_bf16(af[mt][ks], bfr[nt][ks], acc[mt][nt], 0, 0, 0);
            __builtin_amdgcn_s_setprio(0);
        }
        __builtin_amdgcn_s_barrier();
        // ---------------- ph1: quadrant (mt 0-3, nt 2-3)
        {
            v8bf af[4][2], bfr[2][2];
            #pragma unroll
            for (int mt = 0; mt < 4; mt++) { af[mt][0] = rdA(kt, mt, 0); af[mt][1] = rdA(kt, mt, 1); }
            #pragma unroll
            for (int nt = 0; nt < 2; nt++) { bfr[nt][0] = rdB(kt, nt + 2, 0); bfr[nt][1] = rdB(kt, nt + 2, 1); }
            if (kt + 1 < NT) stageA(kt + 1, 1);
            __builtin_amdgcn_s_barrier();
            asm volatile("s_waitcnt lgkmcnt(0)" ::: "memory");
            __builtin_amdgcn_sched_barrier(0);
            __builtin_amdgcn_s_setprio(1);
            #pragma unroll
            for (int mt = 0; mt < 4; mt++)
                #pragma unroll
                for (int nt = 0; nt < 2; nt++)
                    #pragma unroll
                    for (int ks = 0; ks < 2; ks++)
                        acc[mt][nt + 2] = __builtin_amdgcn_mfma_f32_16x16x32_bf16(af[mt][ks], bfr[nt][ks], acc[mt][nt + 2], 0, 0, 0);
            __builtin_amdgcn_s_setprio(0);
        }
        __builtin_amdgcn_s_barrier();
        // ---------------- ph2: quadrant (mt 4-7, nt 0-1)
        {
            v8bf af[4][2], bfr[2][2];
            #pragma unroll
            for (int mt = 0; mt < 4; mt++) { af[mt][0] = rdA(kt, mt + 4, 0); af[mt][1] = rdA(kt, mt + 4, 1); }
            #pragma unroll
            for (int nt = 0; nt < 2; nt++) { bfr[nt][0] = rdB(kt, nt, 0); bfr[nt][1] = rdB(kt, nt, 1); }
            if (kt + 1 < NT) stageB(kt + 1, 0);
            __builtin_amdgcn_s_barrier();
            asm volatile("s_waitcnt lgkmcnt(0)" ::: "memory");
            __builtin_amdgcn_sched_barrier(0);
            __builtin_amdgcn_s_setprio(1);
            #pragma unroll
            for (int mt = 0; mt < 4; mt++)
                #pragma unroll
                for (int nt = 0; nt < 2; nt++)
                    #pragma unroll
                    for (int ks = 0; ks < 2; ks++)
                        acc[mt + 4][nt] = __builtin_amdgcn_mfma_f32_16x16x32_bf16(af[mt][ks], bfr[nt][ks], acc[mt + 4][nt], 0, 0, 0);
            __builtin_amdgcn_s_setprio(0);
        }
        __builtin_amdgcn_s_barrier();
        // ---------------- ph3: quadrant (mt 4-7, nt 2-3)
        {
            v8bf af[4][2], bfr[2][2];
            #pragma unroll
            for (int mt = 0; mt < 4; mt++) { af[mt][0] = rdA(kt, mt + 4, 0); af[mt][1] = rdA(kt, mt + 4, 1); }
            #pragma unroll
            for (int nt = 0; nt < 2; nt++) { bfr[nt][0] = rdB(kt, nt + 2, 0); bfr[nt][1] = rdB(kt, nt + 2, 1); }
            if (kt + 1 < NT) stageB(kt + 1, 1);
            __builtin_amdgcn_s_barrier();
            asm volatile("s_waitcnt lgkmcnt(0)" ::: "memory");
            __builtin_amdgcn_sched_barrier(0);
            __builtin_amdgcn_s_setprio(1);
            #pragma unroll
            for (int mt = 0; mt < 4; mt++)
                #pragma unroll
                for (int nt = 0; nt < 2; nt++)
                    #pragma unroll
                    for (int ks = 0; ks < 2; ks++)
                        acc[mt + 4][nt + 2] = __builtin_amdgcn_mfma_f32_16x16x32_bf16(af[mt][ks], bfr[nt][ks], acc[mt + 4][nt + 2], 0, 0, 0);
            __builtin_amdgcn_s_setprio(0);
        }
        __builtin_amdgcn_s_barrier();
    }

    #pragma unroll
    for (int mt = 0; mt < 8; mt++) {
        #pragma unroll
        for (int nt = 0; nt < 4; nt++) {
            #pragma unroll
            for (int g = 0; g < 4; g++) {
                int row = m0 + wm + mt * 16 + q4 * 4 + g;
                if (row >= M) continue;
                int col = n0 + wn + nt * 16 + ln15;
                float v = acc[mt][nt][g] + bias[col];
                if (dogelu) v = gelu_f(v);
                Cb[(size_t)row * N + col] = (bf16)v;
            }
        }
    }
}

// ---------------------------------------------------------------------------
// bf16 MFMA GEMM: 128xBN tile (BN=128 or 64), BK=32, global_load_lds staging.
// 3-buffer, prefetch-depth-2 pipeline with counted vmcnt (session-best config).
// flags: 1 acc into Cf, 2 gelu, 4 patch row remap (+pos fuse), 8 bf16 out
// ---------------------------------------------------------------------------
template<int BN>
__global__ __launch_bounds__(256) void gemm_bf16(
    const bf16* __restrict__ A, const bf16* __restrict__ Bt,
    const float* __restrict__ bias, float* __restrict__ Cf,
    bf16* __restrict__ Cb, int M, int N, int K, int flags,
    const float* __restrict__ pos, int G)
{
    __shared__ bf16 As[3][128 * 32];
    __shared__ bf16 Bs[3][BN * 32];
    const int tid = threadIdx.x;
    const int lane = tid & 63, wid = tid >> 6;
    const int ln15 = lane & 15, q4 = lane >> 4;
    int xo, yo;
    remap_tile(gridDim.x, gridDim.y, G, xo, yo);
    const int m0 = yo * 128, n0 = xo * BN;
    const int wm = (wid & 1) * 64, wn = (wid >> 1) * (BN / 2);
    const int srow = lane >> 2;
    const int schunk = (lane & 3) * 8;
    const int NF = BN / 32;

    v4f acc[4][NF];
    #pragma unroll
    for (int i = 0; i < 4; i++)
        #pragma unroll
        for (int j = 0; j < NF; j++) acc[i][j] = zero4();

    const int NT = K >> 5;
    auto stage = [&](int kt, int bi) {
        const int k0 = kt << 5;
        #pragma unroll
        for (int i = 0; i < 2; i++) {
            int rg = wid * 32 + i * 16;
            int gm = m0 + rg + srow; if (gm >= M) gm = M - 1;
            gload16(A + (size_t)gm * K + k0 + schunk, &As[bi][rg * 32]);
        }
        if (BN == 128) {
            #pragma unroll
            for (int i = 0; i < 2; i++) {
                int rg = wid * 32 + i * 16;
                gload16(Bt + (size_t)(n0 + rg + srow) * K + k0 + schunk, &Bs[bi][rg * 32]);
            }
        } else {
            int rg = wid * 16;
            gload16(Bt + (size_t)(n0 + rg + srow) * K + k0 + schunk, &Bs[bi][rg * 32]);
        }
    };

    stage(0, 0);
    if (NT > 1) stage(1, 1);

    int cur = 0;
    for (int kt = 0; kt < NT; kt++) {
        int nx2 = cur + 2; if (nx2 >= 3) nx2 -= 3;
        if (kt + 2 < NT) {
            stage(kt + 2, nx2);
            if (BN == 128) asm volatile("s_waitcnt vmcnt(8)" ::: "memory");
            else           asm volatile("s_waitcnt vmcnt(6)" ::: "memory");
        } else if (kt + 1 < NT) {
            if (BN == 128) asm volatile("s_waitcnt vmcnt(4)" ::: "memory");
            else           asm volatile("s_waitcnt vmcnt(3)" ::: "memory");
        } else {
            asm volatile("s_waitcnt vmcnt(0)" ::: "memory");
        }
        __builtin_amdgcn_sched_barrier(0);
        __builtin_amdgcn_s_barrier();

        v8bf af[4], bfr[NF];
        #pragma unroll
        for (int mt = 0; mt < 4; mt++)
            af[mt] = *(const v8bf*)(&As[cur][(wm + mt * 16 + ln15) * 32 + q4 * 8]);
        #pragma unroll
        for (int nt = 0; nt < NF; nt++)
            bfr[nt] = *(const v8bf*)(&Bs[cur][(wn + nt * 16 + ln15) * 32 + q4 * 8]);
        #pragma unroll
        for (int mt = 0; mt < 4; mt++)
            #pragma unroll
            for (int nt = 0; nt < NF; nt++)
                acc[mt][nt] = __builtin_amdgcn_mfma_f32_16x16x32_bf16(af[mt], bfr[nt], acc[mt][nt], 0, 0, 0);
        __builtin_amdgcn_s_barrier();
        cur = cur + 1 == 3 ? 0 : cur + 1;
    }
    #pragma unroll
    for (int mt = 0; mt < 4; mt++) {
        #pragma unroll
        for (int nt = 0; nt < NF; nt++) {
            #pragma unroll
            for (int g = 0; g < 4; g++) {
                int row = m0 + wm + mt * 16 + q4 * 4 + g;
                if (row >= M) continue;
                int col = n0 + wn + nt * 16 + ln15;
                float v = acc[mt][nt][g] + bias[col];
                if (flags & 2) v = gelu_f(v);
                size_t crow;
                if (flags & 4) {
                    int rowp = row % 3072;
                    crow = (size_t)(row + row / 3072 + 1);
                    v += pos[(size_t)(rowp + 1) * EMB + col];
                } else crow = (size_t)row;
                size_t ci = crow * (size_t)N + col;
                if (flags & 8) Cb[ci] = (bf16)v;
                else { if (flags & 1) v += Cf[ci]; Cf[ci] = v; }
            }
        }
    }
}

// ---------------------------------------------------------------------------
// LayerNorm over last dim (768), fp32 in -> bf16 out. Wave shfl_xor
// reductions + one cross-wave LDS combine each (2 barriers/row).
// ---------------------------------------------------------------------------
__global__ __launch_bounds__(256) void layernorm_kernel(
    const float* __restrict__ x, const float* __restrict__ g,
    const float* __restrict__ bb, bf16* __restrict__ y, int nrows)
{
    int row = blockIdx.x;
    if (row >= nrows) return;
    int tid = threadIdx.x;
    int lane = tid & 63, wv = tid >> 6;
    const float* xr = x + (size_t)row * EMB;
    float v0 = xr[tid], v1 = xr[tid + 256], v2 = xr[tid + 512];
    __shared__ float ws[4], ws2[4];
    float s = v0 + v1 + v2;
    #pragma unroll
    for (int o = 1; o < 64; o <<= 1) s += __shfl_xor(s, o, 64);
    if (lane == 0) ws[wv] = s;
    __syncthreads();
    float mu = (ws[0] + ws[1] + ws[2] + ws[3]) * (1.f / 768.f);
    float d0 = v0 - mu, d1 = v1 - mu, d2 = v2 - mu;
    float q = d0 * d0 + d1 * d1 + d2 * d2;
    #pragma unroll
    for (int o = 1; o < 64; o <<= 1) q += __shfl_xor(q, o, 64);
    if (lane == 0) ws2[wv] = q;
    __syncthreads();
    float var = (ws2[0] + ws2[1] + ws2[2] + ws2[3]) * (1.f / 768.f);
    float rs = rsqrtf(var + 1e-5f);
    bf16* yr = y + (size_t)row * EMB;
    yr[tid]       = (bf16)(d0 * rs * g[tid]       + bb[tid]);
    yr[tid + 256] = (bf16)(d1 * rs * g[tid + 256] + bb[tid + 256]);
    yr[tid + 512] = (bf16)(d2 * rs * g[tid + 512] + bb[tid + 512]);
}

// ---------------------------------------------------------------------------
// Pack V transposed per branch-slot: Vt[yy][b*NH+h][dh 64][key 768] bf16.
// ---------------------------------------------------------------------------
__global__ __launch_bounds__(256) void pack_vt(const bf16* __restrict__ qkv,
                                               bf16* __restrict__ Vt)
{
    __shared__ bf16 t[64 * 65];
    int yy = blockIdx.y;
    int br, seg;
    if (yy < 5)       { br = 0; seg = yy; }
    else if (yy < 8)  { br = 1; seg = yy - 5; }
    else if (yy < 10) { br = 2; seg = yy - 8; }
    else if (yy == 10){ br = 3; seg = 0; }
    else              { br = 4; seg = 0; }
    const int r = 1 << br, w = 768 << br;
    const int gsz = (NH + r - 1) / r;
    const int bh = blockIdx.z;
    const int b = bh / NH, hd = bh % NH;
    const int off = hd / gsz;
    const int kbase = seg * w + off;
    const int kt = blockIdx.x;
    const int tid = threadIdx.x;
    const int dq = (tid & 7) * 8;
    #pragma unroll
    for (int p = 0; p < 2; p++) {
        int jl = (tid >> 3) + p * 32;
        int pk = kbase + (kt * 64 + jl) * r;
        v8bf val = (pk < TOK_L)
            ? *(const v8bf*)(qkv + (size_t)(b * TOK_L + pk) * QKVS + 1536 + hd * DH + dq)
            : zero8();
        #pragma unroll
        for (int i = 0; i < 8; i++) t[jl * 65 + dq + i] = val[i];
    }
    __syncthreads();
    #pragma unroll
    for (int p = 0; p < 2; p++) {
        int d = (tid >> 3) + p * 32;
        int kk = (tid & 7) * 8;
        v8bf o;
        #pragma unroll
        for (int i = 0; i < 8; i++) o[i] = t[(kk + i) * 65 + d];
        *(v8bf*)(Vt + ((size_t)(yy * 24 + bh) * 64 + d) * 768 + kt * 64 + kk) = o;
    }
}

// ---------------------------------------------------------------------------
// MFMA dilated attention, in-register softmax (swapped QK^T + cvt_pk +
// permlane swaps). K tiles staged via async global_load_lds, double-buffered,
// XOR-swizzled (pre-swizzled global source, swizzled read).
// Padded keys: p masked to 0; (768 - n_valid) added to denominator.
// ---------------------------------------------------------------------------
__global__ __launch_bounds__(256) void attn_mfma(
    const bf16* __restrict__ qkv, const bf16* __restrict__ Vt,
    bf16* __restrict__ oac, bf16* __restrict__ obr, float* __restrict__ lse5)
{
    __shared__ bf16 kl[2 * 4096];        // [2][64 keys][64 dh], 16B-slot swizzled
    const int tid = threadIdx.x;
    const int lane = tid & 63, wid = tid >> 6;
    const int ln15 = lane & 15, q4 = lane >> 4;
    const int bid = blockIdx.x;
    const int xcd = bid & 7, rest = bid >> 3;
    const int slot = rest / 6, t = rest - slot * 6;
    const int g = (slot << 3) | xcd;          // 0..287
    const int yy = g / 24, bh = g - yy * 24;
    int br, seg;
    if (yy < 5)       { br = 0; seg = yy; }
    else if (yy < 8)  { br = 1; seg = yy - 5; }
    else if (yy < 10) { br = 2; seg = yy - 8; }
    else if (yy == 10){ br = 3; seg = 0; }
    else              { br = 4; seg = 0; }
    const int r = 1 << br, w = 768 << br;
    const int gsz = (NH + r - 1) / r;
    const int b = bh / NH, hd = bh % NH;
    const int off = hd / gsz;
    const int sbase = seg * w + off;
    if (sbase + (t * 128) * r >= TOK_L) return;     // block-uniform early exit

    int n_valid = (TOK_L - sbase + r - 1) / r;
    if (n_valid > 768) n_valid = 768;
    const int kt_lim = (n_valid + 63) >> 6;
    const float pad_add = (float)(768 - n_valid);
    const int qoff = t * 128 + wid * 32;
    const bool wactive = (sbase + qoff * r) < TOK_L;

    const bf16* qb_ = qkv + hd * DH;
    const bf16* kb_ = qkv + 768 + hd * DH;

    // read-side XOR swizzle key (elements, 8-elem = 16B granules)
    const int swz = (ln15 & 7) * 8;

    auto stageK = [&](int ktv, int bufi) {
        #pragma unroll
        for (int p = 0; p < 2; p++) {
            int row = (tid >> 3) + p * 32;
            int pk = sbase + (ktv * 64 + row) * r;
            if (pk >= TOK_L) pk = 0;                // garbage row; masked later
            int colsw = ((tid & 7) ^ ((tid >> 3) & 7)) * 8;   // pre-swizzled source
            gload16(kb_ + (size_t)(b * TOK_L + pk) * QKVS + colsw,
                    kl + bufi * 4096 + wid * 512 + p * 2048);
        }
    };

    // Q fragments, pre-scaled by Dh^-0.5 = 0.125 (exact in bf16)
    v8bf qf[2][2];
    #pragma unroll
    for (int mt = 0; mt < 2; mt++) {
        int pq = sbase + (qoff + mt * 16 + ln15) * r;
        #pragma unroll
        for (int ks = 0; ks < 2; ks++) {
            v8bf qv = (pq < TOK_L)
                ? *(const v8bf*)(qb_ + (size_t)(b * TOK_L + pq) * QKVS + ks * 32 + q4 * 8)
                : zero8();
            #pragma unroll
            for (int i = 0; i < 8; i++) qv[i] = (bf16)((float)qv[i] * 0.125f);
            qf[mt][ks] = qv;
        }
    }
    v4f o[2][4];
    float lsum[2];
    #pragma unroll
    for (int mt = 0; mt < 2; mt++) {
        lsum[mt] = 0.f;
        #pragma unroll
        for (int dt = 0; dt < 4; dt++) o[mt][dt] = zero4();
    }

    const bf16* vtb = Vt + (size_t)(yy * 24 + bh) * 64 * 768;

    stageK(0, 0);
    __syncthreads();

    for (int kt = 0; kt < kt_lim; kt++) {
        const int cur = kt & 1;
        if (kt + 1 < kt_lim) stageK(kt + 1, cur ^ 1);
        if (wactive) {
            const bf16* klc = kl + cur * 4096;
            v8bf kf[4][2];
            #pragma unroll
            for (int nt = 0; nt < 4; nt++)
                #pragma unroll
                for (int ks = 0; ks < 2; ks++)
                    kf[nt][ks] = *(const v8bf*)(klc + (nt * 16 + ln15) * 64
                                                + ((ks * 32 + q4 * 8) ^ swz));
            // paw[mt][ks][4 words] = PV A-fragment, built fully in-register
            unsigned int paw[2][2][4];
            #pragma unroll
            for (int mt = 0; mt < 2; mt++) {
                // swapped QK^T: S^T[k][q], lane ln15 = q, (q4, reg) = k
                v4f s[4];
                #pragma unroll
                for (int nt = 0; nt < 4; nt++) {
                    s[nt] = __builtin_amdgcn_mfma_f32_16x16x32_bf16(kf[nt][0], qf[mt][0], zero4(), 0, 0, 0);
                    s[nt] = __builtin_amdgcn_mfma_f32_16x16x32_bf16(kf[nt][1], qf[mt][1], s[nt], 0, 0, 0);
                }
                unsigned int W[4][2];
                float ls = 0.f;
                #pragma unroll
                for (int nt = 0; nt < 4; nt++) {
                    int kb = kt * 64 + nt * 16 + q4 * 4;
                    float p0 = (kb + 0 < n_valid) ? __expf(s[nt][0]) : 0.f;
                    float p1 = (kb + 1 < n_valid) ? __expf(s[nt][1]) : 0.f;
                    float p2 = (kb + 2 < n_valid) ? __expf(s[nt][2]) : 0.f;
                    float p3 = (kb + 3 < n_valid) ? __expf(s[nt][3]) : 0.f;
                    ls += (p0 + p1) + (p2 + p3);
                    asm("v_cvt_pk_bf16_f32 %0, %1, %2" : "=v"(W[nt][0]) : "v"(p0), "v"(p1));
                    asm("v_cvt_pk_bf16_f32 %0, %1, %2" : "=v"(W[nt][1]) : "v"(p2), "v"(p3));
                }
                lsum[mt] += ls;
                // quarter-lane regroup: perm32 then perm16 delivers, per target
                // quarter tq4, the words of source lane ln15+16*q4' with
                // nt = 2ks + (tq4>>1), q4' = 2*(tq4&1) (+1 for the late pair).
                #pragma unroll
                for (int ks = 0; ks < 2; ks++) {
                    #pragma unroll
                    for (int h = 0; h < 2; h++) {
                        unsigned int a = W[2 * ks][h], c = W[2 * ks + 1][h];
                        asm("v_permlane32_swap_b32 %0, %1" : "+v"(a), "+v"(c));
                        asm("v_permlane16_swap_b32 %0, %1" : "+v"(a), "+v"(c));
                        paw[mt][ks][h]     = a;   // E_h
                        paw[mt][ks][2 + h] = c;   // L_h
                    }
                }
            }
            #pragma unroll
            for (int ks = 0; ks < 2; ks++) {
                v8bf vf[4];
                #pragma unroll
                for (int dt = 0; dt < 4; dt++)
                    vf[dt] = *(const v8bf*)(vtb + (size_t)(dt * 16 + ln15) * 768 + kt * 64 + ks * 32 + q4 * 8);
                #pragma unroll
                for (int mt = 0; mt < 2; mt++) {
                    v4u pw = { paw[mt][ks][0], paw[mt][ks][1], paw[mt][ks][2], paw[mt][ks][3] };
                    v8bf pa = __builtin_bit_cast(v8bf, pw);
                    #pragma unroll
                    for (int dt = 0; dt < 4; dt++)
                        o[mt][dt] = __builtin_amdgcn_mfma_f32_16x16x32_bf16(pa, vf[dt], o[mt][dt], 0, 0, 0);
                }
            }
        }
        __syncthreads();
    }
    if (!wactive) return;

    // row sums: lane holds partial for q = mt*16+ln15; reduce across quarters
    float lf[2];
    #pragma unroll
    for (int mt = 0; mt < 2; mt++) {
        float l = lsum[mt];
        l += __shfl_xor(l, 16, 64);
        l += __shfl_xor(l, 32, 64);
        l += pad_add;
        lf[mt] = l;
        if (q4 == 0) {
            int pq = sbase + (qoff + mt * 16 + ln15) * r;
            if (pq < TOK_L)
                lse5[(size_t)br * MHC + (size_t)(b * TOK_L + pq) * NH + hd] = __logf(l);
        }
    }

    bf16* od = (br == 0) ? oac : obr + (size_t)(br - 1) * HSZ;
    #pragma unroll
    for (int mt = 0; mt < 2; mt++) {
        #pragma unroll
        for (int g2 = 0; g2 < 4; g2++) {
            float l = __shfl(lf[mt], q4 * 4 + g2, 64);   // row sum for this D-row
            int row = mt * 16 + q4 * 4 + g2;
            int pq = sbase + (qoff + row) * r;
            if (pq >= TOK_L) continue;
            float linv = 1.f / l;
            #pragma unroll
            for (int dt = 0; dt < 4; dt++)
                od[(size_t)(b * TOK_L + pq) * EMB + hd * DH + dt * 16 + ln15] =
                    (bf16)(o[mt][dt][g2] * linv);
        }
    }
}

// ---------------------------------------------------------------------------
// LSE-softmax recombination of the 5 branches -> hn (bf16, next GEMM's A).
// 2 consecutive elements per thread; 4B/lane loads+stores.
// ---------------------------------------------------------------------------
__global__ __launch_bounds__(256) void attn_combine(
    const bf16* __restrict__ oac, const bf16* __restrict__ obr,
    const float* __restrict__ lse5, bf16* __restrict__ outb)
{
    size_t e = ((size_t)blockIdx.x * 256 + threadIdx.x) * 2;
    if (e >= HSZ) return;
    size_t g = e >> 6;                       // e even -> e, e+1 share group
    int h = (int)(g % NH);
    int p = (int)((g / NH) % TOK_L);
    float l0 = lse5[g];
    float m = l0;
    float lv[4];
    bool cov[4];
    #pragma unroll
    for (int j = 0; j < 4; j++) {
        int r = 2 << j;
        int gsz = (NH + r - 1) / r;
        cov[j] = ((p & (r - 1)) == (h / gsz));
        if (cov[j]) {
            lv[j] = lse5[(size_t)(j + 1) * MHC + g];
            m = fmaxf(m, lv[j]);
        }
    }
    float w0 = __expf(l0 - m);
    float wsum = w0;
    v2bf a0 = *(const v2bf*)(oac + e);
    float acc0 = w0 * (float)a0[0];
    float acc1 = w0 * (float)a0[1];
    #pragma unroll
    for (int j = 0; j < 4; j++) {
        if (cov[j]) {
            float wj = __expf(lv[j] - m);
            wsum += wj;
            v2bf aj = *(const v2bf*)(obr + (size_t)j * HSZ + e);
            acc0 = fmaf(wj, (float)aj[0], acc0);
            acc1 = fmaf(wj, (float)aj[1], acc1);
        }
    }
    float inv = 1.f / wsum;
    v2bf o2; o2[0] = (bf16)(acc0 * inv); o2[1] = (bf16)(acc1 * inv);
    *(v2bf*)(outb + e) = o2;
}

// out[b,c] = hn[b,0,:] @ head_w + head_b   (hn bf16, head fp32)
__global__ __launch_bounds__(256) void head_kernel(
    const bf16* __restrict__ hn, const float* __restrict__ hw,
    const float* __restrict__ hb, float* __restrict__ out)
{
    int b = blockIdx.y;
    int c = blockIdx.x * 256 + threadIdx.x;
    __shared__ float srow[EMB];
    for (int e = threadIdx.x; e < EMB; e += 256)
        srow[e] = (float)hn[(size_t)b * TOK_L * EMB + e];
    __syncthreads();
    if (c < 1000) {
        float acc = hb[c];
        for (int e = 0; e < EMB; e++)
            acc = fmaf(srow[e], hw[(size_t)e * 1000 + c], acc);
        out[b * 1000 + c] = acc;
    }
}

// ---------------------------------------------------------------------------
extern "C" void kernel_launch(void* const* d_in, const int* in_sizes, int n_in,
                              void* d_out, int out_size, void* d_ws, size_t ws_size,
                              hipStream_t stream)
{
    const float* x       = (const float*)d_in[0];
    const float* patch_w = (const float*)d_in[1];
    const float* patch_b = (const float*)d_in[2];
    const float* cls_tok = (const float*)d_in[3];
    const float* pos_emb = (const float*)d_in[4];
    const float* ln1_g   = (const float*)d_in[5];
    const float* ln1_b   = (const float*)d_in[6];
    const float* wq      = (const float*)d_in[7];
    const float* bq      = (const float*)d_in[8];
    const float* wk      = (const float*)d_in[9];
    const float* bk      = (const float*)d_in[10];
    const float* wv      = (const float*)d_in[11];
    const float* bv      = (const float*)d_in[12];
    const float* wo      = (const float*)d_in[13];
    const float* bo      = (const float*)d_in[14];
    const float* ln2_g   = (const float*)d_in[15];
    const float* ln2_b   = (const float*)d_in[16];
    const float* w1      = (const float*)d_in[17];
    const float* b1      = (const float*)d_in[18];
    const float* w2      = (const float*)d_in[19];
    const float* b2      = (const float*)d_in[20];
    const float* normf_g = (const float*)d_in[21];
    const float* normf_b = (const float*)d_in[22];
    const float* head_w  = (const float*)d_in[23];
    const float* head_b  = (const float*)d_in[24];
    float* out = (float*)d_out;

    char* wp = (char*)d_ws;
    auto alloc = [&](size_t bytes) { char* r = wp; wp += (bytes + 255) & ~(size_t)255; return r; };
    float* h    = (float*)alloc(HSZ * 4);
    bf16*  hn   = (bf16*)alloc(HSZ * 2);
    bf16*  QKV  = (bf16*)alloc((size_t)BATCH * TOK_L * QKVS * 2);
    bf16*  oac  = (bf16*)alloc(HSZ * 2);
    float* lse5 = (float*)alloc(5 * MHC * 4);
    bf16*  Vt   = (bf16*)alloc((size_t)12 * 24 * 64 * 768 * 2);
    bf16*  mid  = (bf16*)alloc(4 * HSZ * 2);       // FFN mid / Xp / obr overlay
    bf16*  obr  = mid;
    bf16*  Xp   = mid;

    bf16*  qkv_t0 = (bf16*)alloc((size_t)2 * QKVS * 768 * 2);
    bf16*  wo_t0  = (bf16*)alloc((size_t)2 * 768 * 768 * 2);
    bf16*  w1_t   = (bf16*)alloc((size_t)2 * 3072 * 768 * 2);
    bf16*  w2_t   = (bf16*)alloc((size_t)2 * 768 * 3072 * 2);
    bf16*  pw_b   = (bf16*)alloc((size_t)768 * 1024 * 2);
    float* bqkv   = (float*)alloc((size_t)2 * QKVS * 4);

    const int M = BATCH * TOK_L;        // 6146
    const int MT = (M + 127) / 128;     // 49
    const int MT2 = (M + 255) / 256;    // 25

    prep_weights<<<dim3(14592), 256, 0, stream>>>(wq, wk, wv, wo, w1, w2, patch_w,
                                                  qkv_t0, wo_t0, w1_t, w2_t, pw_b);
    prep_small<<<dim3(18), 256, 0, stream>>>(bq, bk, bv, bqkv, cls_tok, pos_emb, h);

    gather_patches<<<dim3(BATCH * 3072), 256, 0, stream>>>(x, Xp);
    gemm_bf16<64><<<dim3(12, 48), 256, 0, stream>>>(Xp, pw_b, patch_b, h, nullptr,
                                                    BATCH * 3072, 768, 1024, 4, pos_emb, 8);

    for (int layer = 0; layer < 2; layer++) {
        size_t bOff  = (size_t)layer * 768;
        size_t b1Off = (size_t)layer * 3072;
        bf16* qt   = qkv_t0 + (size_t)layer * QKVS * 768;
        bf16* wo_t = wo_t0 + (size_t)layer * 589824;

        layernorm_kernel<<<dim3(M), 256, 0, stream>>>(h, ln1_g + bOff, ln1_b + bOff, hn, M);
        gemm_bf16<128><<<dim3(18, MT), 256, 0, stream>>>(hn, qt, bqkv + (size_t)layer * QKVS,
                                                         nullptr, QKV, M, QKVS, 768, 8, nullptr, 8);

        pack_vt<<<dim3(12, 12, 24), 256, 0, stream>>>(QKV, Vt);
        attn_mfma<<<dim3(1728), 256, 0, stream>>>(QKV, Vt, oac, obr, lse5);
        attn_combine<<<dim3((unsigned)((HSZ / 2 + 255) / 256)), 256, 0, stream>>>(oac, obr, lse5, hn);

        gemm_bf16<64><<<dim3(12, MT), 256, 0, stream>>>(hn, wo_t, bo + bOff, h, nullptr,
                                                        M, 768, 768, 1, nullptr, 8);

        layernorm_kernel<<<dim3(M), 256, 0, stream>>>(h, ln2_g + bOff, ln2_b + bOff, hn, M);
        gemm256<<<dim3(12, MT2), 512, 0, stream>>>(hn, w1_t + (size_t)layer * 2359296, b1 + b1Off,
                                                   mid, M, 3072, 768, 1, 4);
        gemm_bf16<64><<<dim3(12, MT), 256, 0, stream>>>(mid, w2_t + (size_t)layer * 2359296, b2 + bOff,
                                                        h, nullptr, M, 768, 3072, 1, nullptr, 4);
    }

    layernorm_kernel<<<dim3(M), 256, 0, stream>>>(h, normf_g, normf_b, hn, M);
    head_kernel<<<dim3(4, BATCH), 256, 0, stream>>>(hn, head_w, head_b, out);
}

// Round 13
// 946.339 us; speedup vs baseline: 1.0744x; 1.0744x over previous
//
#include <hip/hip_runtime.h>
#include <math.h>

#define TOK_L 3073
#define EMB 768
#define NH 12
#define DH 64
#define BATCH 2
#define QKVS 2304
#define HSZ ((size_t)BATCH * TOK_L * EMB)   // 4,720,128
#define MHC ((size_t)BATCH * TOK_L * NH)    // 73,752

typedef __bf16 bf16;
typedef __bf16 v8bf __attribute__((ext_vector_type(8)));
typedef __bf16 v4bf __attribute__((ext_vector_type(4)));
typedef __bf16 v2bf __attribute__((ext_vector_type(2)));
typedef float  v4f  __attribute__((ext_vector_type(4)));
typedef unsigned int v4u __attribute__((ext_vector_type(4)));

__device__ __forceinline__ v8bf zero8() {
    v8bf v;
    #pragma unroll
    for (int i = 0; i < 8; i++) v[i] = (bf16)0.f;
    return v;
}
__device__ __forceinline__ v4f zero4() {
    v4f v; v[0] = 0.f; v[1] = 0.f; v[2] = 0.f; v[3] = 0.f; return v;
}
__device__ __forceinline__ float gelu_f(float x) {
    return 0.5f * x * (1.0f + erff(x * 0.70710678118654752f));
}
// async global->LDS, 16B per lane; lds base must be wave-uniform (lane scatters +lane*16B)
__device__ __forceinline__ void gload16(const bf16* g, bf16* l) {
    __builtin_amdgcn_global_load_lds(
        (const __attribute__((address_space(1))) void*)g,
        (__attribute__((address_space(3))) void*)l, 16, 0, 0);
}

// ---------------------------------------------------------------------------
// Mega weight-prep: 12 transpose-converts + patch_w cvt. grid = 14592.
// ---------------------------------------------------------------------------
__device__ __forceinline__ void convT_tile(const float* __restrict__ src,
                                           bf16* __restrict__ dst,
                                           int K, int N, int tx, int ty)
{
    __shared__ float t[32][33];
    int n0 = tx * 32, k0 = ty * 32;
    int r = threadIdx.x >> 3, c4 = (threadIdx.x & 7) * 4;
    float4 v = *(const float4*)(src + (size_t)(k0 + r) * N + n0 + c4);
    t[r][c4 + 0] = v.x; t[r][c4 + 1] = v.y; t[r][c4 + 2] = v.z; t[r][c4 + 3] = v.w;
    __syncthreads();
    v4bf o;
    o[0] = (bf16)t[c4 + 0][r]; o[1] = (bf16)t[c4 + 1][r];
    o[2] = (bf16)t[c4 + 2][r]; o[3] = (bf16)t[c4 + 3][r];
    *(v4bf*)(dst + (size_t)(n0 + r) * K + k0 + c4) = o;
}

__global__ __launch_bounds__(256) void prep_weights(
    const float* __restrict__ wq, const float* __restrict__ wk,
    const float* __restrict__ wv, const float* __restrict__ wo,
    const float* __restrict__ w1, const float* __restrict__ w2,
    const float* __restrict__ patch_w,
    bf16* __restrict__ qkv_t0, bf16* __restrict__ wo_t0,
    bf16* __restrict__ w1_t, bf16* __restrict__ w2_t, bf16* __restrict__ pw_b)
{
    int bid = blockIdx.x;
    if (bid >= 13824) {
        int i = ((bid - 13824) * 256 + threadIdx.x) * 4;
        float4 v = *(const float4*)(patch_w + i);
        v4bf o; o[0] = (bf16)v.x; o[1] = (bf16)v.y; o[2] = (bf16)v.z; o[3] = (bf16)v.w;
        *(v4bf*)(pw_b + i) = o;
        return;
    }
    int layer = bid / 6912, t = bid % 6912;
    if (t < 1728) {
        int m = t / 576, tt = t % 576;
        const float* src = (m == 0 ? wq : m == 1 ? wk : wv) + (size_t)layer * 589824;
        bf16* dst = qkv_t0 + (size_t)layer * QKVS * 768 + (size_t)m * 589824;
        convT_tile(src, dst, 768, 768, tt % 24, tt / 24);
    } else if (t < 2304) {
        int tt = t - 1728;
        convT_tile(wo + (size_t)layer * 589824, wo_t0 + (size_t)layer * 589824,
                   768, 768, tt % 24, tt / 24);
    } else if (t < 4608) {
        int tt = t - 2304;
        convT_tile(w1 + (size_t)layer * 2359296, w1_t + (size_t)layer * 2359296,
                   768, 3072, tt % 96, tt / 96);
    } else {
        int tt = t - 4608;
        convT_tile(w2 + (size_t)layer * 2359296, w2_t + (size_t)layer * 2359296,
                   3072, 768, tt % 24, tt / 24);
    }
}

// concat q/k/v biases -> bqkv[layer][2304]; also init cls rows of h. grid 18.
__global__ __launch_bounds__(256) void prep_small(const float* __restrict__ bq,
    const float* __restrict__ bk, const float* __restrict__ bv, float* __restrict__ d,
    const float* __restrict__ cls, const float* __restrict__ pos, float* __restrict__ h)
{
    int i = blockIdx.x * 256 + threadIdx.x;
    if (i < 2 * QKVS) {
        int layer = i / QKVS, j = i % QKVS;
        const float* s = (j < 768) ? bq : (j < 1536) ? bk : bv;
        d[i] = s[(size_t)layer * 768 + (j & 767)];
    }
    if (i < 2 * 768) {
        int b = i / 768, e = i % 768;
        h[(size_t)b * TOK_L * EMB + e] = cls[e] + pos[e];
    }
}

// ---------------------------------------------------------------------------
// Patch gather: x (B,1,48,256,256) fp32 -> Xp (B*3072, 1024) bf16.
// float4 loads (16B/lane) + v4bf stores; 1024 = 256 threads x 4 exactly.
// ---------------------------------------------------------------------------
__global__ __launch_bounds__(256) void gather_patches(const float* __restrict__ x,
                                                      bf16* __restrict__ Xp) {
    int p = blockIdx.x;
    int b = p / 3072, pp = p % 3072;
    int px = pp >> 8, py = (pp >> 4) & 15, pz = pp & 15;
    int k = threadIdx.x * 4;                 // pw 4-aligned, contiguous quad
    int pd = k >> 8, ph = (k >> 4) & 15, pw = k & 15;
    size_t src = ((size_t)(b * 48 + px * 4 + pd)) * 65536
               + (size_t)(py * 16 + ph) * 256 + (size_t)(pz * 16 + pw);
    float4 v = *(const float4*)(x + src);
    v4bf o; o[0] = (bf16)v.x; o[1] = (bf16)v.y; o[2] = (bf16)v.z; o[3] = (bf16)v.w;
    *(v4bf*)(Xp + (size_t)p * 1024 + k) = o;
}

// ---------------------------------------------------------------------------
// XCD-chunked, panel-grouped tile remap (bijective, m204-style 8-way split).
// ---------------------------------------------------------------------------
__device__ __forceinline__ void remap_tile(int NX, int MY, int G, int& xo, int& yo)
{
    int id = blockIdx.x + NX * blockIdx.y;   // physical linear id
    int nwg = NX * MY;
    int xcd = id & 7, j = id >> 3;           // physical XCD + slot (id%8 = XCD)
    int q = nwg >> 3, r = nwg & 7;
    int n = xcd * q + (xcd < r ? xcd : r) + j;   // logical rank (bijective)
    int full = MY / G;
    int bpg = NX * G;
    int nf = full * bpg;
    if (n < nf) {
        int gi = n / bpg, w = n - gi * bpg;
        int xi = w / G;
        xo = xi; yo = gi * G + (w - xi * G);
    } else {
        int t = MY - full * G;               // tail rows (>0 iff taken)
        int w = n - nf;
        int xi = w / t;
        xo = xi; yo = full * G + (w - xi * t);
    }
}

// ---------------------------------------------------------------------------
// bf16 MFMA GEMM: 128xBN tile (BN=128 or 64), BK=32, global_load_lds staging.
// 3-buffer, prefetch-depth-2 pipeline with counted vmcnt. Session-best config
// (944.3 us). gemm256 8-phase port permanently reverted: 3 structurally
// distinct implementations all 107-114 us / ~10% MfmaUtil (compiler-drain,
// asm-alias, vmcnt-ledger, reg-liveness theories each falsified); with 128KB
// LDS only 1 block/CU is resident so every raw-barrier phase edge is fully
// exposed, and the per-phase stall is not localizable without .s/PMC
// instrumentation of the port itself.
// flags: 1 acc into Cf, 2 gelu, 4 patch row remap (+pos fuse), 8 bf16 out
// ---------------------------------------------------------------------------
template<int BN>
__global__ __launch_bounds__(256) void gemm_bf16(
    const bf16* __restrict__ A, const bf16* __restrict__ Bt,
    const float* __restrict__ bias, float* __restrict__ Cf,
    bf16* __restrict__ Cb, int M, int N, int K, int flags,
    const float* __restrict__ pos, int G)
{
    __shared__ bf16 As[3][128 * 32];
    __shared__ bf16 Bs[3][BN * 32];
    const int tid = threadIdx.x;
    const int lane = tid & 63, wid = tid >> 6;
    const int ln15 = lane & 15, q4 = lane >> 4;
    int xo, yo;
    remap_tile(gridDim.x, gridDim.y, G, xo, yo);
    const int m0 = yo * 128, n0 = xo * BN;
    const int wm = (wid & 1) * 64, wn = (wid >> 1) * (BN / 2);
    const int srow = lane >> 2;
    const int schunk = (lane & 3) * 8;
    const int NF = BN / 32;

    v4f acc[4][NF];
    #pragma unroll
    for (int i = 0; i < 4; i++)
        #pragma unroll
        for (int j = 0; j < NF; j++) acc[i][j] = zero4();

    const int NT = K >> 5;
    auto stage = [&](int kt, int bi) {
        const int k0 = kt << 5;
        #pragma unroll
        for (int i = 0; i < 2; i++) {
            int rg = wid * 32 + i * 16;
            int gm = m0 + rg + srow; if (gm >= M) gm = M - 1;
            gload16(A + (size_t)gm * K + k0 + schunk, &As[bi][rg * 32]);
        }
        if (BN == 128) {
            #pragma unroll
            for (int i = 0; i < 2; i++) {
                int rg = wid * 32 + i * 16;
                gload16(Bt + (size_t)(n0 + rg + srow) * K + k0 + schunk, &Bs[bi][rg * 32]);
            }
        } else {
            int rg = wid * 16;
            gload16(Bt + (size_t)(n0 + rg + srow) * K + k0 + schunk, &Bs[bi][rg * 32]);
        }
    };

    stage(0, 0);
    if (NT > 1) stage(1, 1);

    int cur = 0;
    for (int kt = 0; kt < NT; kt++) {
        int nx2 = cur + 2; if (nx2 >= 3) nx2 -= 3;
        if (kt + 2 < NT) {
            stage(kt + 2, nx2);
            if (BN == 128) asm volatile("s_waitcnt vmcnt(8)" ::: "memory");
            else           asm volatile("s_waitcnt vmcnt(6)" ::: "memory");
        } else if (kt + 1 < NT) {
            if (BN == 128) asm volatile("s_waitcnt vmcnt(4)" ::: "memory");
            else           asm volatile("s_waitcnt vmcnt(3)" ::: "memory");
        } else {
            asm volatile("s_waitcnt vmcnt(0)" ::: "memory");
        }
        __builtin_amdgcn_sched_barrier(0);
        __builtin_amdgcn_s_barrier();

        v8bf af[4], bfr[NF];
        #pragma unroll
        for (int mt = 0; mt < 4; mt++)
            af[mt] = *(const v8bf*)(&As[cur][(wm + mt * 16 + ln15) * 32 + q4 * 8]);
        #pragma unroll
        for (int nt = 0; nt < NF; nt++)
            bfr[nt] = *(const v8bf*)(&Bs[cur][(wn + nt * 16 + ln15) * 32 + q4 * 8]);
        #pragma unroll
        for (int mt = 0; mt < 4; mt++)
            #pragma unroll
            for (int nt = 0; nt < NF; nt++)
                acc[mt][nt] = __builtin_amdgcn_mfma_f32_16x16x32_bf16(af[mt], bfr[nt], acc[mt][nt], 0, 0, 0);
        __builtin_amdgcn_s_barrier();
        cur = cur + 1 == 3 ? 0 : cur + 1;
    }
    #pragma unroll
    for (int mt = 0; mt < 4; mt++) {
        #pragma unroll
        for (int nt = 0; nt < NF; nt++) {
            #pragma unroll
            for (int g = 0; g < 4; g++) {
                int row = m0 + wm + mt * 16 + q4 * 4 + g;
                if (row >= M) continue;
                int col = n0 + wn + nt * 16 + ln15;
                float v = acc[mt][nt][g] + bias[col];
                if (flags & 2) v = gelu_f(v);
                size_t crow;
                if (flags & 4) {
                    int rowp = row % 3072;
                    crow = (size_t)(row + row / 3072 + 1);
                    v += pos[(size_t)(rowp + 1) * EMB + col];
                } else crow = (size_t)row;
                size_t ci = crow * (size_t)N + col;
                if (flags & 8) Cb[ci] = (bf16)v;
                else { if (flags & 1) v += Cf[ci]; Cf[ci] = v; }
            }
        }
    }
}

// ---------------------------------------------------------------------------
// LayerNorm over last dim (768), fp32 in -> bf16 out. Wave shfl_xor
// reductions + one cross-wave LDS combine each (2 barriers/row).
// ---------------------------------------------------------------------------
__global__ __launch_bounds__(256) void layernorm_kernel(
    const float* __restrict__ x, const float* __restrict__ g,
    const float* __restrict__ bb, bf16* __restrict__ y, int nrows)
{
    int row = blockIdx.x;
    if (row >= nrows) return;
    int tid = threadIdx.x;
    int lane = tid & 63, wv = tid >> 6;
    const float* xr = x + (size_t)row * EMB;
    float v0 = xr[tid], v1 = xr[tid + 256], v2 = xr[tid + 512];
    __shared__ float ws[4], ws2[4];
    float s = v0 + v1 + v2;
    #pragma unroll
    for (int o = 1; o < 64; o <<= 1) s += __shfl_xor(s, o, 64);
    if (lane == 0) ws[wv] = s;
    __syncthreads();
    float mu = (ws[0] + ws[1] + ws[2] + ws[3]) * (1.f / 768.f);
    float d0 = v0 - mu, d1 = v1 - mu, d2 = v2 - mu;
    float q = d0 * d0 + d1 * d1 + d2 * d2;
    #pragma unroll
    for (int o = 1; o < 64; o <<= 1) q += __shfl_xor(q, o, 64);
    if (lane == 0) ws2[wv] = q;
    __syncthreads();
    float var = (ws2[0] + ws2[1] + ws2[2] + ws2[3]) * (1.f / 768.f);
    float rs = rsqrtf(var + 1e-5f);
    bf16* yr = y + (size_t)row * EMB;
    yr[tid]       = (bf16)(d0 * rs * g[tid]       + bb[tid]);
    yr[tid + 256] = (bf16)(d1 * rs * g[tid + 256] + bb[tid + 256]);
    yr[tid + 512] = (bf16)(d2 * rs * g[tid + 512] + bb[tid + 512]);
}

// ---------------------------------------------------------------------------
// Pack V transposed per branch-slot: Vt[yy][b*NH+h][dh 64][key 768] bf16.
// ---------------------------------------------------------------------------
__global__ __launch_bounds__(256) void pack_vt(const bf16* __restrict__ qkv,
                                               bf16* __restrict__ Vt)
{
    __shared__ bf16 t[64 * 65];
    int yy = blockIdx.y;
    int br, seg;
    if (yy < 5)       { br = 0; seg = yy; }
    else if (yy < 8)  { br = 1; seg = yy - 5; }
    else if (yy < 10) { br = 2; seg = yy - 8; }
    else if (yy == 10){ br = 3; seg = 0; }
    else              { br = 4; seg = 0; }
    const int r = 1 << br, w = 768 << br;
    const int gsz = (NH + r - 1) / r;
    const int bh = blockIdx.z;
    const int b = bh / NH, hd = bh % NH;
    const int off = hd / gsz;
    const int kbase = seg * w + off;
    const int kt = blockIdx.x;
    const int tid = threadIdx.x;
    const int dq = (tid & 7) * 8;
    #pragma unroll
    for (int p = 0; p < 2; p++) {
        int jl = (tid >> 3) + p * 32;
        int pk = kbase + (kt * 64 + jl) * r;
        v8bf val = (pk < TOK_L)
            ? *(const v8bf*)(qkv + (size_t)(b * TOK_L + pk) * QKVS + 1536 + hd * DH + dq)
            : zero8();
        #pragma unroll
        for (int i = 0; i < 8; i++) t[jl * 65 + dq + i] = val[i];
    }
    __syncthreads();
    #pragma unroll
    for (int p = 0; p < 2; p++) {
        int d = (tid >> 3) + p * 32;
        int kk = (tid & 7) * 8;
        v8bf o;
        #pragma unroll
        for (int i = 0; i < 8; i++) o[i] = t[(kk + i) * 65 + d];
        *(v8bf*)(Vt + ((size_t)(yy * 24 + bh) * 64 + d) * 768 + kt * 64 + kk) = o;
    }
}

// ---------------------------------------------------------------------------
// MFMA dilated attention, in-register softmax (swapped QK^T + cvt_pk +
// permlane swaps). K tiles staged via async global_load_lds, double-buffered,
// XOR-swizzled (pre-swizzled global source, swizzled read).
// Padded keys: p masked to 0; (768 - n_valid) added to denominator.
// ---------------------------------------------------------------------------
__global__ __launch_bounds__(256) void attn_mfma(
    const bf16* __restrict__ qkv, const bf16* __restrict__ Vt,
    bf16* __restrict__ oac, bf16* __restrict__ obr, float* __restrict__ lse5)
{
    __shared__ bf16 kl[2 * 4096];        // [2][64 keys][64 dh], 16B-slot swizzled
    const int tid = threadIdx.x;
    const int lane = tid & 63, wid = tid >> 6;
    const int ln15 = lane & 15, q4 = lane >> 4;
    const int bid = blockIdx.x;
    const int xcd = bid & 7, rest = bid >> 3;
    const int slot = rest / 6, t = rest - slot * 6;
    const int g = (slot << 3) | xcd;          // 0..287
    const int yy = g / 24, bh = g - yy * 24;
    int br, seg;
    if (yy < 5)       { br = 0; seg = yy; }
    else if (yy < 8)  { br = 1; seg = yy - 5; }
    else if (yy < 10) { br = 2; seg = yy - 8; }
    else if (yy == 10){ br = 3; seg = 0; }
    else              { br = 4; seg = 0; }
    const int r = 1 << br, w = 768 << br;
    const int gsz = (NH + r - 1) / r;
    const int b = bh / NH, hd = bh % NH;
    const int off = hd / gsz;
    const int sbase = seg * w + off;
    if (sbase + (t * 128) * r >= TOK_L) return;     // block-uniform early exit

    int n_valid = (TOK_L - sbase + r - 1) / r;
    if (n_valid > 768) n_valid = 768;
    const int kt_lim = (n_valid + 63) >> 6;
    const float pad_add = (float)(768 - n_valid);
    const int qoff = t * 128 + wid * 32;
    const bool wactive = (sbase + qoff * r) < TOK_L;

    const bf16* qb_ = qkv + hd * DH;
    const bf16* kb_ = qkv + 768 + hd * DH;

    // read-side XOR swizzle key (elements, 8-elem = 16B granules)
    const int swz = (ln15 & 7) * 8;

    auto stageK = [&](int ktv, int bufi) {
        #pragma unroll
        for (int p = 0; p < 2; p++) {
            int row = (tid >> 3) + p * 32;
            int pk = sbase + (ktv * 64 + row) * r;
            if (pk >= TOK_L) pk = 0;                // garbage row; masked later
            int colsw = ((tid & 7) ^ ((tid >> 3) & 7)) * 8;   // pre-swizzled source
            gload16(kb_ + (size_t)(b * TOK_L + pk) * QKVS + colsw,
                    kl + bufi * 4096 + wid * 512 + p * 2048);
        }
    };

    // Q fragments, pre-scaled by Dh^-0.5 = 0.125 (exact in bf16)
    v8bf qf[2][2];
    #pragma unroll
    for (int mt = 0; mt < 2; mt++) {
        int pq = sbase + (qoff + mt * 16 + ln15) * r;
        #pragma unroll
        for (int ks = 0; ks < 2; ks++) {
            v8bf qv = (pq < TOK_L)
                ? *(const v8bf*)(qb_ + (size_t)(b * TOK_L + pq) * QKVS + ks * 32 + q4 * 8)
                : zero8();
            #pragma unroll
            for (int i = 0; i < 8; i++) qv[i] = (bf16)((float)qv[i] * 0.125f);
            qf[mt][ks] = qv;
        }
    }
    v4f o[2][4];
    float lsum[2];
    #pragma unroll
    for (int mt = 0; mt < 2; mt++) {
        lsum[mt] = 0.f;
        #pragma unroll
        for (int dt = 0; dt < 4; dt++) o[mt][dt] = zero4();
    }

    const bf16* vtb = Vt + (size_t)(yy * 24 + bh) * 64 * 768;

    stageK(0, 0);
    __syncthreads();

    for (int kt = 0; kt < kt_lim; kt++) {
        const int cur = kt & 1;
        if (kt + 1 < kt_lim) stageK(kt + 1, cur ^ 1);
        if (wactive) {
            const bf16* klc = kl + cur * 4096;
            v8bf kf[4][2];
            #pragma unroll
            for (int nt = 0; nt < 4; nt++)
                #pragma unroll
                for (int ks = 0; ks < 2; ks++)
                    kf[nt][ks] = *(const v8bf*)(klc + (nt * 16 + ln15) * 64
                                                + ((ks * 32 + q4 * 8) ^ swz));
            // paw[mt][ks][4 words] = PV A-fragment, built fully in-register
            unsigned int paw[2][2][4];
            #pragma unroll
            for (int mt = 0; mt < 2; mt++) {
                // swapped QK^T: S^T[k][q], lane ln15 = q, (q4, reg) = k
                v4f s[4];
                #pragma unroll
                for (int nt = 0; nt < 4; nt++) {
                    s[nt] = __builtin_amdgcn_mfma_f32_16x16x32_bf16(kf[nt][0], qf[mt][0], zero4(), 0, 0, 0);
                    s[nt] = __builtin_amdgcn_mfma_f32_16x16x32_bf16(kf[nt][1], qf[mt][1], s[nt], 0, 0, 0);
                }
                unsigned int W[4][2];
                float ls = 0.f;
                #pragma unroll
                for (int nt = 0; nt < 4; nt++) {
                    int kb = kt * 64 + nt * 16 + q4 * 4;
                    float p0 = (kb + 0 < n_valid) ? __expf(s[nt][0]) : 0.f;
                    float p1 = (kb + 1 < n_valid) ? __expf(s[nt][1]) : 0.f;
                    float p2 = (kb + 2 < n_valid) ? __expf(s[nt][2]) : 0.f;
                    float p3 = (kb + 3 < n_valid) ? __expf(s[nt][3]) : 0.f;
                    ls += (p0 + p1) + (p2 + p3);
                    asm("v_cvt_pk_bf16_f32 %0, %1, %2" : "=v"(W[nt][0]) : "v"(p0), "v"(p1));
                    asm("v_cvt_pk_bf16_f32 %0, %1, %2" : "=v"(W[nt][1]) : "v"(p2), "v"(p3));
                }
                lsum[mt] += ls;
                // quarter-lane regroup: perm32 then perm16 delivers, per target
                // quarter tq4, the words of source lane ln15+16*q4' with
                // nt = 2ks + (tq4>>1), q4' = 2*(tq4&1) (+1 for the late pair).
                #pragma unroll
                for (int ks = 0; ks < 2; ks++) {
                    #pragma unroll
                    for (int h = 0; h < 2; h++) {
                        unsigned int a = W[2 * ks][h], c = W[2 * ks + 1][h];
                        asm("v_permlane32_swap_b32 %0, %1" : "+v"(a), "+v"(c));
                        asm("v_permlane16_swap_b32 %0, %1" : "+v"(a), "+v"(c));
                        paw[mt][ks][h]     = a;   // E_h
                        paw[mt][ks][2 + h] = c;   // L_h
                    }
                }
            }
            #pragma unroll
            for (int ks = 0; ks < 2; ks++) {
                v8bf vf[4];
                #pragma unroll
                for (int dt = 0; dt < 4; dt++)
                    vf[dt] = *(const v8bf*)(vtb + (size_t)(dt * 16 + ln15) * 768 + kt * 64 + ks * 32 + q4 * 8);
                #pragma unroll
                for (int mt = 0; mt < 2; mt++) {
                    v4u pw = { paw[mt][ks][0], paw[mt][ks][1], paw[mt][ks][2], paw[mt][ks][3] };
                    v8bf pa = __builtin_bit_cast(v8bf, pw);
                    #pragma unroll
                    for (int dt = 0; dt < 4; dt++)
                        o[mt][dt] = __builtin_amdgcn_mfma_f32_16x16x32_bf16(pa, vf[dt], o[mt][dt], 0, 0, 0);
                }
            }
        }
        __syncthreads();
    }
    if (!wactive) return;

    // row sums: lane holds partial for q = mt*16+ln15; reduce across quarters
    float lf[2];
    #pragma unroll
    for (int mt = 0; mt < 2; mt++) {
        float l = lsum[mt];
        l += __shfl_xor(l, 16, 64);
        l += __shfl_xor(l, 32, 64);
        l += pad_add;
        lf[mt] = l;
        if (q4 == 0) {
            int pq = sbase + (qoff + mt * 16 + ln15) * r;
            if (pq < TOK_L)
                lse5[(size_t)br * MHC + (size_t)(b * TOK_L + pq) * NH + hd] = __logf(l);
        }
    }

    bf16* od = (br == 0) ? oac : obr + (size_t)(br - 1) * HSZ;
    #pragma unroll
    for (int mt = 0; mt < 2; mt++) {
        #pragma unroll
        for (int g2 = 0; g2 < 4; g2++) {
            float l = __shfl(lf[mt], q4 * 4 + g2, 64);   // row sum for this D-row
            int row = mt * 16 + q4 * 4 + g2;
            int pq = sbase + (qoff + row) * r;
            if (pq >= TOK_L) continue;
            float linv = 1.f / l;
            #pragma unroll
            for (int dt = 0; dt < 4; dt++)
                od[(size_t)(b * TOK_L + pq) * EMB + hd * DH + dt * 16 + ln15] =
                    (bf16)(o[mt][dt][g2] * linv);
        }
    }
}

// ---------------------------------------------------------------------------
// LSE-softmax recombination of the 5 branches -> hn (bf16, next GEMM's A).
// 2 consecutive elements per thread; 4B/lane loads+stores.
// ---------------------------------------------------------------------------
__global__ __launch_bounds__(256) void attn_combine(
    const bf16* __restrict__ oac, const bf16* __restrict__ obr,
    const float* __restrict__ lse5, bf16* __restrict__ outb)
{
    size_t e = ((size_t)blockIdx.x * 256 + threadIdx.x) * 2;
    if (e >= HSZ) return;
    size_t g = e >> 6;                       // e even -> e, e+1 share group
    int h = (int)(g % NH);
    int p = (int)((g / NH) % TOK_L);
    float l0 = lse5[g];
    float m = l0;
    float lv[4];
    bool cov[4];
    #pragma unroll
    for (int j = 0; j < 4; j++) {
        int r = 2 << j;
        int gsz = (NH + r - 1) / r;
        cov[j] = ((p & (r - 1)) == (h / gsz));
        if (cov[j]) {
            lv[j] = lse5[(size_t)(j + 1) * MHC + g];
            m = fmaxf(m, lv[j]);
        }
    }
    float w0 = __expf(l0 - m);
    float wsum = w0;
    v2bf a0 = *(const v2bf*)(oac + e);
    float acc0 = w0 * (float)a0[0];
    float acc1 = w0 * (float)a0[1];
    #pragma unroll
    for (int j = 0; j < 4; j++) {
        if (cov[j]) {
            float wj = __expf(lv[j] - m);
            wsum += wj;
            v2bf aj = *(const v2bf*)(obr + (size_t)j * HSZ + e);
            acc0 = fmaf(wj, (float)aj[0], acc0);
            acc1 = fmaf(wj, (float)aj[1], acc1);
        }
    }
    float inv = 1.f / wsum;
    v2bf o2; o2[0] = (bf16)(acc0 * inv); o2[1] = (bf16)(acc1 * inv);
    *(v2bf*)(outb + e) = o2;
}

// out[b,c] = hn[b,0,:] @ head_w + head_b   (hn bf16, head fp32)
__global__ __launch_bounds__(256) void head_kernel(
    const bf16* __restrict__ hn, const float* __restrict__ hw,
    const float* __restrict__ hb, float* __restrict__ out)
{
    int b = blockIdx.y;
    int c = blockIdx.x * 256 + threadIdx.x;
    __shared__ float srow[EMB];
    for (int e = threadIdx.x; e < EMB; e += 256)
        srow[e] = (float)hn[(size_t)b * TOK_L * EMB + e];
    __syncthreads();
    if (c < 1000) {
        float acc = hb[c];
        for (int e = 0; e < EMB; e++)
            acc = fmaf(srow[e], hw[(size_t)e * 1000 + c], acc);
        out[b * 1000 + c] = acc;
    }
}

// ---------------------------------------------------------------------------
extern "C" void kernel_launch(void* const* d_in, const int* in_sizes, int n_in,
                              void* d_out, int out_size, void* d_ws, size_t ws_size,
                              hipStream_t stream)
{
    const float* x       = (const float*)d_in[0];
    const float* patch_w = (const float*)d_in[1];
    const float* patch_b = (const float*)d_in[2];
    const float* cls_tok = (const float*)d_in[3];
    const float* pos_emb = (const float*)d_in[4];
    const float* ln1_g   = (const float*)d_in[5];
    const float* ln1_b   = (const float*)d_in[6];
    const float* wq      = (const float*)d_in[7];
    const float* bq      = (const float*)d_in[8];
    const float* wk      = (const float*)d_in[9];
    const float* bk      = (const float*)d_in[10];
    const float* wv      = (const float*)d_in[11];
    const float* bv      = (const float*)d_in[12];
    const float* wo      = (const float*)d_in[13];
    const float* bo      = (const float*)d_in[14];
    const float* ln2_g   = (const float*)d_in[15];
    const float* ln2_b   = (const float*)d_in[16];
    const float* w1      = (const float*)d_in[17];
    const float* b1      = (const float*)d_in[18];
    const float* w2      = (const float*)d_in[19];
    const float* b2      = (const float*)d_in[20];
    const float* normf_g = (const float*)d_in[21];
    const float* normf_b = (const float*)d_in[22];
    const float* head_w  = (const float*)d_in[23];
    const float* head_b  = (const float*)d_in[24];
    float* out = (float*)d_out;

    char* wp = (char*)d_ws;
    auto alloc = [&](size_t bytes) { char* r = wp; wp += (bytes + 255) & ~(size_t)255; return r; };
    float* h    = (float*)alloc(HSZ * 4);
    bf16*  hn   = (bf16*)alloc(HSZ * 2);
    bf16*  QKV  = (bf16*)alloc((size_t)BATCH * TOK_L * QKVS * 2);
    bf16*  oac  = (bf16*)alloc(HSZ * 2);
    float* lse5 = (float*)alloc(5 * MHC * 4);
    bf16*  Vt   = (bf16*)alloc((size_t)12 * 24 * 64 * 768 * 2);
    bf16*  mid  = (bf16*)alloc(4 * HSZ * 2);       // FFN mid / Xp / obr overlay
    bf16*  obr  = mid;
    bf16*  Xp   = mid;

    bf16*  qkv_t0 = (bf16*)alloc((size_t)2 * QKVS * 768 * 2);
    bf16*  wo_t0  = (bf16*)alloc((size_t)2 * 768 * 768 * 2);
    bf16*  w1_t   = (bf16*)alloc((size_t)2 * 3072 * 768 * 2);
    bf16*  w2_t   = (bf16*)alloc((size_t)2 * 768 * 3072 * 2);
    bf16*  pw_b   = (bf16*)alloc((size_t)768 * 1024 * 2);
    float* bqkv   = (float*)alloc((size_t)2 * QKVS * 4);

    const int M = BATCH * TOK_L;        // 6146
    const int MT = (M + 127) / 128;     // 49

    prep_weights<<<dim3(14592), 256, 0, stream>>>(wq, wk, wv, wo, w1, w2, patch_w,
                                                  qkv_t0, wo_t0, w1_t, w2_t, pw_b);
    prep_small<<<dim3(18), 256, 0, stream>>>(bq, bk, bv, bqkv, cls_tok, pos_emb, h);

    gather_patches<<<dim3(BATCH * 3072), 256, 0, stream>>>(x, Xp);
    gemm_bf16<64><<<dim3(12, 48), 256, 0, stream>>>(Xp, pw_b, patch_b, h, nullptr,
                                                    BATCH * 3072, 768, 1024, 4, pos_emb, 8);

    for (int layer = 0; layer < 2; layer++) {
        size_t bOff  = (size_t)layer * 768;
        size_t b1Off = (size_t)layer * 3072;
        bf16* qt   = qkv_t0 + (size_t)layer * QKVS * 768;
        bf16* wo_t = wo_t0 + (size_t)layer * 589824;

        layernorm_kernel<<<dim3(M), 256, 0, stream>>>(h, ln1_g + bOff, ln1_b + bOff, hn, M);
        gemm_bf16<128><<<dim3(18, MT), 256, 0, stream>>>(hn, qt, bqkv + (size_t)layer * QKVS,
                                                         nullptr, QKV, M, QKVS, 768, 8, nullptr, 8);

        pack_vt<<<dim3(12, 12, 24), 256, 0, stream>>>(QKV, Vt);
        attn_mfma<<<dim3(1728), 256, 0, stream>>>(QKV, Vt, oac, obr, lse5);
        attn_combine<<<dim3((unsigned)((HSZ / 2 + 255) / 256)), 256, 0, stream>>>(oac, obr, lse5, hn);

        gemm_bf16<64><<<dim3(12, MT), 256, 0, stream>>>(hn, wo_t, bo + bOff, h, nullptr,
                                                        M, 768, 768, 1, nullptr, 8);

        layernorm_kernel<<<dim3(M), 256, 0, stream>>>(h, ln2_g + bOff, ln2_b + bOff, hn, M);
        gemm_bf16<128><<<dim3(24, MT), 256, 0, stream>>>(hn, w1_t + (size_t)layer * 2359296, b1 + b1Off,
                                                         nullptr, mid, M, 3072, 768, 8 | 2, nullptr, 8);
        gemm_bf16<64><<<dim3(12, MT), 256, 0, stream>>>(mid, w2_t + (size_t)layer * 2359296, b2 + bOff,
                                                        h, nullptr, M, 768, 3072, 1, nullptr, 4);
    }

    layernorm_kernel<<<dim3(M), 256, 0, stream>>>(h, normf_g, normf_b, hn, M);
    head_kernel<<<dim3(4, BATCH), 256, 0, stream>>>(hn, head_w, head_b, out);
}

// Round 14
// 926.580 us; speedup vs baseline: 1.0973x; 1.0213x over previous
//
#include <hip/hip_runtime.h>
#include <math.h>

#define TOK_L 3073
#define EMB 768
#define NH 12
#define DH 64
#define BATCH 2
#define QKVS 2304
#define HSZ ((size_t)BATCH * TOK_L * EMB)   // 4,720,128
#define MHC ((size_t)BATCH * TOK_L * NH)    // 73,752

typedef __bf16 bf16;
typedef __bf16 v8bf __attribute__((ext_vector_type(8)));
typedef __bf16 v4bf __attribute__((ext_vector_type(4)));
typedef __bf16 v2bf __attribute__((ext_vector_type(2)));
typedef float  v4f  __attribute__((ext_vector_type(4)));
typedef unsigned int v4u __attribute__((ext_vector_type(4)));

__device__ __forceinline__ v8bf zero8() {
    v8bf v;
    #pragma unroll
    for (int i = 0; i < 8; i++) v[i] = (bf16)0.f;
    return v;
}
__device__ __forceinline__ v4f zero4() {
    v4f v; v[0] = 0.f; v[1] = 0.f; v[2] = 0.f; v[3] = 0.f; return v;
}
__device__ __forceinline__ float gelu_f(float x) {
    return 0.5f * x * (1.0f + erff(x * 0.70710678118654752f));
}
// async global->LDS, 16B per lane; lds base must be wave-uniform (lane scatters +lane*16B)
__device__ __forceinline__ void gload16(const bf16* g, bf16* l) {
    __builtin_amdgcn_global_load_lds(
        (const __attribute__((address_space(1))) void*)g,
        (__attribute__((address_space(3))) void*)l, 16, 0, 0);
}

// ---------------------------------------------------------------------------
// Mega weight-prep: 12 transpose-converts + patch_w cvt. grid = 14592.
// ---------------------------------------------------------------------------
__device__ __forceinline__ void convT_tile(const float* __restrict__ src,
                                           bf16* __restrict__ dst,
                                           int K, int N, int tx, int ty)
{
    __shared__ float t[32][33];
    int n0 = tx * 32, k0 = ty * 32;
    int r = threadIdx.x >> 3, c4 = (threadIdx.x & 7) * 4;
    float4 v = *(const float4*)(src + (size_t)(k0 + r) * N + n0 + c4);
    t[r][c4 + 0] = v.x; t[r][c4 + 1] = v.y; t[r][c4 + 2] = v.z; t[r][c4 + 3] = v.w;
    __syncthreads();
    v4bf o;
    o[0] = (bf16)t[c4 + 0][r]; o[1] = (bf16)t[c4 + 1][r];
    o[2] = (bf16)t[c4 + 2][r]; o[3] = (bf16)t[c4 + 3][r];
    *(v4bf*)(dst + (size_t)(n0 + r) * K + k0 + c4) = o;
}

__global__ __launch_bounds__(256) void prep_weights(
    const float* __restrict__ wq, const float* __restrict__ wk,
    const float* __restrict__ wv, const float* __restrict__ wo,
    const float* __restrict__ w1, const float* __restrict__ w2,
    const float* __restrict__ patch_w,
    bf16* __restrict__ qkv_t0, bf16* __restrict__ wo_t0,
    bf16* __restrict__ w1_t, bf16* __restrict__ w2_t, bf16* __restrict__ pw_b)
{
    int bid = blockIdx.x;
    if (bid >= 13824) {
        int i = ((bid - 13824) * 256 + threadIdx.x) * 4;
        float4 v = *(const float4*)(patch_w + i);
        v4bf o; o[0] = (bf16)v.x; o[1] = (bf16)v.y; o[2] = (bf16)v.z; o[3] = (bf16)v.w;
        *(v4bf*)(pw_b + i) = o;
        return;
    }
    int layer = bid / 6912, t = bid % 6912;
    if (t < 1728) {
        int m = t / 576, tt = t % 576;
        const float* src = (m == 0 ? wq : m == 1 ? wk : wv) + (size_t)layer * 589824;
        bf16* dst = qkv_t0 + (size_t)layer * QKVS * 768 + (size_t)m * 589824;
        convT_tile(src, dst, 768, 768, tt % 24, tt / 24);
    } else if (t < 2304) {
        int tt = t - 1728;
        convT_tile(wo + (size_t)layer * 589824, wo_t0 + (size_t)layer * 589824,
                   768, 768, tt % 24, tt / 24);
    } else if (t < 4608) {
        int tt = t - 2304;
        convT_tile(w1 + (size_t)layer * 2359296, w1_t + (size_t)layer * 2359296,
                   768, 3072, tt % 96, tt / 96);
    } else {
        int tt = t - 4608;
        convT_tile(w2 + (size_t)layer * 2359296, w2_t + (size_t)layer * 2359296,
                   3072, 768, tt % 24, tt / 24);
    }
}

// concat q/k/v biases -> bqkv[layer][2304]; also init cls rows of h. grid 18.
__global__ __launch_bounds__(256) void prep_small(const float* __restrict__ bq,
    const float* __restrict__ bk, const float* __restrict__ bv, float* __restrict__ d,
    const float* __restrict__ cls, const float* __restrict__ pos, float* __restrict__ h)
{
    int i = blockIdx.x * 256 + threadIdx.x;
    if (i < 2 * QKVS) {
        int layer = i / QKVS, j = i % QKVS;
        const float* s = (j < 768) ? bq : (j < 1536) ? bk : bv;
        d[i] = s[(size_t)layer * 768 + (j & 767)];
    }
    if (i < 2 * 768) {
        int b = i / 768, e = i % 768;
        h[(size_t)b * TOK_L * EMB + e] = cls[e] + pos[e];
    }
}

// ---------------------------------------------------------------------------
// Patch gather: x (B,1,48,256,256) fp32 -> Xp (B*3072, 1024) bf16.
// float4 loads (16B/lane) + v4bf stores; 1024 = 256 threads x 4 exactly.
// ---------------------------------------------------------------------------
__global__ __launch_bounds__(256) void gather_patches(const float* __restrict__ x,
                                                      bf16* __restrict__ Xp) {
    int p = blockIdx.x;
    int b = p / 3072, pp = p % 3072;
    int px = pp >> 8, py = (pp >> 4) & 15, pz = pp & 15;
    int k = threadIdx.x * 4;                 // pw 4-aligned, contiguous quad
    int pd = k >> 8, ph = (k >> 4) & 15, pw = k & 15;
    size_t src = ((size_t)(b * 48 + px * 4 + pd)) * 65536
               + (size_t)(py * 16 + ph) * 256 + (size_t)(pz * 16 + pw);
    float4 v = *(const float4*)(x + src);
    v4bf o; o[0] = (bf16)v.x; o[1] = (bf16)v.y; o[2] = (bf16)v.z; o[3] = (bf16)v.w;
    *(v4bf*)(Xp + (size_t)p * 1024 + k) = o;
}

// ---------------------------------------------------------------------------
// XCD-chunked, panel-grouped tile remap (bijective, m204-style 8-way split).
// ---------------------------------------------------------------------------
__device__ __forceinline__ void remap_tile(int NX, int MY, int G, int& xo, int& yo)
{
    int id = blockIdx.x + NX * blockIdx.y;   // physical linear id
    int nwg = NX * MY;
    int xcd = id & 7, j = id >> 3;           // physical XCD + slot (id%8 = XCD)
    int q = nwg >> 3, r = nwg & 7;
    int n = xcd * q + (xcd < r ? xcd : r) + j;   // logical rank (bijective)
    int full = MY / G;
    int bpg = NX * G;
    int nf = full * bpg;
    if (n < nf) {
        int gi = n / bpg, w = n - gi * bpg;
        int xi = w / G;
        xo = xi; yo = gi * G + (w - xi * G);
    } else {
        int t = MY - full * G;               // tail rows (>0 iff taken)
        int w = n - nf;
        int xi = w / t;
        xo = xi; yo = full * G + (w - xi * t);
    }
}

// ---------------------------------------------------------------------------
// bf16 MFMA GEMM: 128xBN tile (BN=128 or 64), BK=32, global_load_lds staging.
// 3-buffer, prefetch-depth-2 pipeline with counted vmcnt (session-best).
// BN=64 sustains ~2x the staging rate of BN=128 in this structure (measured
// cross-shape R10/R13), so QKV runs BN=64; FFN-up stays BN=128 (wash by the
// same arithmetic). gemm256 8-phase permanently reverted (3 ports falsified).
// flags: 1 acc into Cf, 2 gelu, 4 patch row remap (+pos fuse), 8 bf16 out
// ---------------------------------------------------------------------------
template<int BN>
__global__ __launch_bounds__(256) void gemm_bf16(
    const bf16* __restrict__ A, const bf16* __restrict__ Bt,
    const float* __restrict__ bias, float* __restrict__ Cf,
    bf16* __restrict__ Cb, int M, int N, int K, int flags,
    const float* __restrict__ pos, int G)
{
    __shared__ bf16 As[3][128 * 32];
    __shared__ bf16 Bs[3][BN * 32];
    const int tid = threadIdx.x;
    const int lane = tid & 63, wid = tid >> 6;
    const int ln15 = lane & 15, q4 = lane >> 4;
    int xo, yo;
    remap_tile(gridDim.x, gridDim.y, G, xo, yo);
    const int m0 = yo * 128, n0 = xo * BN;
    const int wm = (wid & 1) * 64, wn = (wid >> 1) * (BN / 2);
    const int srow = lane >> 2;
    const int schunk = (lane & 3) * 8;
    const int NF = BN / 32;

    v4f acc[4][NF];
    #pragma unroll
    for (int i = 0; i < 4; i++)
        #pragma unroll
        for (int j = 0; j < NF; j++) acc[i][j] = zero4();

    const int NT = K >> 5;
    auto stage = [&](int kt, int bi) {
        const int k0 = kt << 5;
        #pragma unroll
        for (int i = 0; i < 2; i++) {
            int rg = wid * 32 + i * 16;
            int gm = m0 + rg + srow; if (gm >= M) gm = M - 1;
            gload16(A + (size_t)gm * K + k0 + schunk, &As[bi][rg * 32]);
        }
        if (BN == 128) {
            #pragma unroll
            for (int i = 0; i < 2; i++) {
                int rg = wid * 32 + i * 16;
                gload16(Bt + (size_t)(n0 + rg + srow) * K + k0 + schunk, &Bs[bi][rg * 32]);
            }
        } else {
            int rg = wid * 16;
            gload16(Bt + (size_t)(n0 + rg + srow) * K + k0 + schunk, &Bs[bi][rg * 32]);
        }
    };

    stage(0, 0);
    if (NT > 1) stage(1, 1);

    int cur = 0;
    for (int kt = 0; kt < NT; kt++) {
        int nx2 = cur + 2; if (nx2 >= 3) nx2 -= 3;
        if (kt + 2 < NT) {
            stage(kt + 2, nx2);
            if (BN == 128) asm volatile("s_waitcnt vmcnt(8)" ::: "memory");
            else           asm volatile("s_waitcnt vmcnt(6)" ::: "memory");
        } else if (kt + 1 < NT) {
            if (BN == 128) asm volatile("s_waitcnt vmcnt(4)" ::: "memory");
            else           asm volatile("s_waitcnt vmcnt(3)" ::: "memory");
        } else {
            asm volatile("s_waitcnt vmcnt(0)" ::: "memory");
        }
        __builtin_amdgcn_sched_barrier(0);
        __builtin_amdgcn_s_barrier();

        v8bf af[4], bfr[NF];
        #pragma unroll
        for (int mt = 0; mt < 4; mt++)
            af[mt] = *(const v8bf*)(&As[cur][(wm + mt * 16 + ln15) * 32 + q4 * 8]);
        #pragma unroll
        for (int nt = 0; nt < NF; nt++)
            bfr[nt] = *(const v8bf*)(&Bs[cur][(wn + nt * 16 + ln15) * 32 + q4 * 8]);
        #pragma unroll
        for (int mt = 0; mt < 4; mt++)
            #pragma unroll
            for (int nt = 0; nt < NF; nt++)
                acc[mt][nt] = __builtin_amdgcn_mfma_f32_16x16x32_bf16(af[mt], bfr[nt], acc[mt][nt], 0, 0, 0);
        __builtin_amdgcn_s_barrier();
        cur = cur + 1 == 3 ? 0 : cur + 1;
    }
    #pragma unroll
    for (int mt = 0; mt < 4; mt++) {
        #pragma unroll
        for (int nt = 0; nt < NF; nt++) {
            #pragma unroll
            for (int g = 0; g < 4; g++) {
                int row = m0 + wm + mt * 16 + q4 * 4 + g;
                if (row >= M) continue;
                int col = n0 + wn + nt * 16 + ln15;
                float v = acc[mt][nt][g] + bias[col];
                if (flags & 2) v = gelu_f(v);
                size_t crow;
                if (flags & 4) {
                    int rowp = row % 3072;
                    crow = (size_t)(row + row / 3072 + 1);
                    v += pos[(size_t)(rowp + 1) * EMB + col];
                } else crow = (size_t)row;
                size_t ci = crow * (size_t)N + col;
                if (flags & 8) Cb[ci] = (bf16)v;
                else { if (flags & 1) v += Cf[ci]; Cf[ci] = v; }
            }
        }
    }
}

// ---------------------------------------------------------------------------
// LayerNorm over last dim (768), fp32 in -> bf16 out. Wave shfl_xor
// reductions + one cross-wave LDS combine each (2 barriers/row).
// ---------------------------------------------------------------------------
__global__ __launch_bounds__(256) void layernorm_kernel(
    const float* __restrict__ x, const float* __restrict__ g,
    const float* __restrict__ bb, bf16* __restrict__ y, int nrows)
{
    int row = blockIdx.x;
    if (row >= nrows) return;
    int tid = threadIdx.x;
    int lane = tid & 63, wv = tid >> 6;
    const float* xr = x + (size_t)row * EMB;
    float v0 = xr[tid], v1 = xr[tid + 256], v2 = xr[tid + 512];
    __shared__ float ws[4], ws2[4];
    float s = v0 + v1 + v2;
    #pragma unroll
    for (int o = 1; o < 64; o <<= 1) s += __shfl_xor(s, o, 64);
    if (lane == 0) ws[wv] = s;
    __syncthreads();
    float mu = (ws[0] + ws[1] + ws[2] + ws[3]) * (1.f / 768.f);
    float d0 = v0 - mu, d1 = v1 - mu, d2 = v2 - mu;
    float q = d0 * d0 + d1 * d1 + d2 * d2;
    #pragma unroll
    for (int o = 1; o < 64; o <<= 1) q += __shfl_xor(q, o, 64);
    if (lane == 0) ws2[wv] = q;
    __syncthreads();
    float var = (ws2[0] + ws2[1] + ws2[2] + ws2[3]) * (1.f / 768.f);
    float rs = rsqrtf(var + 1e-5f);
    bf16* yr = y + (size_t)row * EMB;
    yr[tid]       = (bf16)(d0 * rs * g[tid]       + bb[tid]);
    yr[tid + 256] = (bf16)(d1 * rs * g[tid + 256] + bb[tid + 256]);
    yr[tid + 512] = (bf16)(d2 * rs * g[tid + 512] + bb[tid + 512]);
}

// ---------------------------------------------------------------------------
// Pack V transposed per branch-slot: Vt[yy][b*NH+h][dh 64][key 768] bf16.
// ---------------------------------------------------------------------------
__global__ __launch_bounds__(256) void pack_vt(const bf16* __restrict__ qkv,
                                               bf16* __restrict__ Vt)
{
    __shared__ bf16 t[64 * 65];
    int yy = blockIdx.y;
    int br, seg;
    if (yy < 5)       { br = 0; seg = yy; }
    else if (yy < 8)  { br = 1; seg = yy - 5; }
    else if (yy < 10) { br = 2; seg = yy - 8; }
    else if (yy == 10){ br = 3; seg = 0; }
    else              { br = 4; seg = 0; }
    const int r = 1 << br, w = 768 << br;
    const int gsz = (NH + r - 1) / r;
    const int bh = blockIdx.z;
    const int b = bh / NH, hd = bh % NH;
    const int off = hd / gsz;
    const int kbase = seg * w + off;
    const int kt = blockIdx.x;
    const int tid = threadIdx.x;
    const int dq = (tid & 7) * 8;
    #pragma unroll
    for (int p = 0; p < 2; p++) {
        int jl = (tid >> 3) + p * 32;
        int pk = kbase + (kt * 64 + jl) * r;
        v8bf val = (pk < TOK_L)
            ? *(const v8bf*)(qkv + (size_t)(b * TOK_L + pk) * QKVS + 1536 + hd * DH + dq)
            : zero8();
        #pragma unroll
        for (int i = 0; i < 8; i++) t[jl * 65 + dq + i] = val[i];
    }
    __syncthreads();
    #pragma unroll
    for (int p = 0; p < 2; p++) {
        int d = (tid >> 3) + p * 32;
        int kk = (tid & 7) * 8;
        v8bf o;
        #pragma unroll
        for (int i = 0; i < 8; i++) o[i] = t[(kk + i) * 65 + d];
        *(v8bf*)(Vt + ((size_t)(yy * 24 + bh) * 64 + d) * 768 + kt * 64 + kk) = o;
    }
}

// ---------------------------------------------------------------------------
// MFMA dilated attention, in-register softmax (swapped QK^T + cvt_pk +
// permlane swaps). K tiles staged via async global_load_lds, double-buffered,
// XOR-swizzled (pre-swizzled global source, swizzled read).
// Padded keys: p masked to 0; (768 - n_valid) added to denominator.
// ---------------------------------------------------------------------------
__global__ __launch_bounds__(256) void attn_mfma(
    const bf16* __restrict__ qkv, const bf16* __restrict__ Vt,
    bf16* __restrict__ oac, bf16* __restrict__ obr, float* __restrict__ lse5)
{
    __shared__ bf16 kl[2 * 4096];        // [2][64 keys][64 dh], 16B-slot swizzled
    const int tid = threadIdx.x;
    const int lane = tid & 63, wid = tid >> 6;
    const int ln15 = lane & 15, q4 = lane >> 4;
    const int bid = blockIdx.x;
    const int xcd = bid & 7, rest = bid >> 3;
    const int slot = rest / 6, t = rest - slot * 6;
    const int g = (slot << 3) | xcd;          // 0..287
    const int yy = g / 24, bh = g - yy * 24;
    int br, seg;
    if (yy < 5)       { br = 0; seg = yy; }
    else if (yy < 8)  { br = 1; seg = yy - 5; }
    else if (yy < 10) { br = 2; seg = yy - 8; }
    else if (yy == 10){ br = 3; seg = 0; }
    else              { br = 4; seg = 0; }
    const int r = 1 << br, w = 768 << br;
    const int gsz = (NH + r - 1) / r;
    const int b = bh / NH, hd = bh % NH;
    const int off = hd / gsz;
    const int sbase = seg * w + off;
    if (sbase + (t * 128) * r >= TOK_L) return;     // block-uniform early exit

    int n_valid = (TOK_L - sbase + r - 1) / r;
    if (n_valid > 768) n_valid = 768;
    const int kt_lim = (n_valid + 63) >> 6;
    const float pad_add = (float)(768 - n_valid);
    const int qoff = t * 128 + wid * 32;
    const bool wactive = (sbase + qoff * r) < TOK_L;

    const bf16* qb_ = qkv + hd * DH;
    const bf16* kb_ = qkv + 768 + hd * DH;

    // read-side XOR swizzle key (elements, 8-elem = 16B granules)
    const int swz = (ln15 & 7) * 8;

    auto stageK = [&](int ktv, int bufi) {
        #pragma unroll
        for (int p = 0; p < 2; p++) {
            int row = (tid >> 3) + p * 32;
            int pk = sbase + (ktv * 64 + row) * r;
            if (pk >= TOK_L) pk = 0;                // garbage row; masked later
            int colsw = ((tid & 7) ^ ((tid >> 3) & 7)) * 8;   // pre-swizzled source
            gload16(kb_ + (size_t)(b * TOK_L + pk) * QKVS + colsw,
                    kl + bufi * 4096 + wid * 512 + p * 2048);
        }
    };

    // Q fragments, pre-scaled by Dh^-0.5 = 0.125 (exact in bf16)
    v8bf qf[2][2];
    #pragma unroll
    for (int mt = 0; mt < 2; mt++) {
        int pq = sbase + (qoff + mt * 16 + ln15) * r;
        #pragma unroll
        for (int ks = 0; ks < 2; ks++) {
            v8bf qv = (pq < TOK_L)
                ? *(const v8bf*)(qb_ + (size_t)(b * TOK_L + pq) * QKVS + ks * 32 + q4 * 8)
                : zero8();
            #pragma unroll
            for (int i = 0; i < 8; i++) qv[i] = (bf16)((float)qv[i] * 0.125f);
            qf[mt][ks] = qv;
        }
    }
    v4f o[2][4];
    float lsum[2];
    #pragma unroll
    for (int mt = 0; mt < 2; mt++) {
        lsum[mt] = 0.f;
        #pragma unroll
        for (int dt = 0; dt < 4; dt++) o[mt][dt] = zero4();
    }

    const bf16* vtb = Vt + (size_t)(yy * 24 + bh) * 64 * 768;

    stageK(0, 0);
    __syncthreads();

    for (int kt = 0; kt < kt_lim; kt++) {
        const int cur = kt & 1;
        if (kt + 1 < kt_lim) stageK(kt + 1, cur ^ 1);
        if (wactive) {
            const bf16* klc = kl + cur * 4096;
            v8bf kf[4][2];
            #pragma unroll
            for (int nt = 0; nt < 4; nt++)
                #pragma unroll
                for (int ks = 0; ks < 2; ks++)
                    kf[nt][ks] = *(const v8bf*)(klc + (nt * 16 + ln15) * 64
                                                + ((ks * 32 + q4 * 8) ^ swz));
            // paw[mt][ks][4 words] = PV A-fragment, built fully in-register
            unsigned int paw[2][2][4];
            #pragma unroll
            for (int mt = 0; mt < 2; mt++) {
                // swapped QK^T: S^T[k][q], lane ln15 = q, (q4, reg) = k
                v4f s[4];
                #pragma unroll
                for (int nt = 0; nt < 4; nt++) {
                    s[nt] = __builtin_amdgcn_mfma_f32_16x16x32_bf16(kf[nt][0], qf[mt][0], zero4(), 0, 0, 0);
                    s[nt] = __builtin_amdgcn_mfma_f32_16x16x32_bf16(kf[nt][1], qf[mt][1], s[nt], 0, 0, 0);
                }
                unsigned int W[4][2];
                float ls = 0.f;
                #pragma unroll
                for (int nt = 0; nt < 4; nt++) {
                    int kb = kt * 64 + nt * 16 + q4 * 4;
                    float p0 = (kb + 0 < n_valid) ? __expf(s[nt][0]) : 0.f;
                    float p1 = (kb + 1 < n_valid) ? __expf(s[nt][1]) : 0.f;
                    float p2 = (kb + 2 < n_valid) ? __expf(s[nt][2]) : 0.f;
                    float p3 = (kb + 3 < n_valid) ? __expf(s[nt][3]) : 0.f;
                    ls += (p0 + p1) + (p2 + p3);
                    asm("v_cvt_pk_bf16_f32 %0, %1, %2" : "=v"(W[nt][0]) : "v"(p0), "v"(p1));
                    asm("v_cvt_pk_bf16_f32 %0, %1, %2" : "=v"(W[nt][1]) : "v"(p2), "v"(p3));
                }
                lsum[mt] += ls;
                // quarter-lane regroup: perm32 then perm16 delivers, per target
                // quarter tq4, the words of source lane ln15+16*q4' with
                // nt = 2ks + (tq4>>1), q4' = 2*(tq4&1) (+1 for the late pair).
                #pragma unroll
                for (int ks = 0; ks < 2; ks++) {
                    #pragma unroll
                    for (int h = 0; h < 2; h++) {
                        unsigned int a = W[2 * ks][h], c = W[2 * ks + 1][h];
                        asm("v_permlane32_swap_b32 %0, %1" : "+v"(a), "+v"(c));
                        asm("v_permlane16_swap_b32 %0, %1" : "+v"(a), "+v"(c));
                        paw[mt][ks][h]     = a;   // E_h
                        paw[mt][ks][2 + h] = c;   // L_h
                    }
                }
            }
            #pragma unroll
            for (int ks = 0; ks < 2; ks++) {
                v8bf vf[4];
                #pragma unroll
                for (int dt = 0; dt < 4; dt++)
                    vf[dt] = *(const v8bf*)(vtb + (size_t)(dt * 16 + ln15) * 768 + kt * 64 + ks * 32 + q4 * 8);
                #pragma unroll
                for (int mt = 0; mt < 2; mt++) {
                    v4u pw = { paw[mt][ks][0], paw[mt][ks][1], paw[mt][ks][2], paw[mt][ks][3] };
                    v8bf pa = __builtin_bit_cast(v8bf, pw);
                    #pragma unroll
                    for (int dt = 0; dt < 4; dt++)
                        o[mt][dt] = __builtin_amdgcn_mfma_f32_16x16x32_bf16(pa, vf[dt], o[mt][dt], 0, 0, 0);
                }
            }
        }
        __syncthreads();
    }
    if (!wactive) return;

    // row sums: lane holds partial for q = mt*16+ln15; reduce across quarters
    float lf[2];
    #pragma unroll
    for (int mt = 0; mt < 2; mt++) {
        float l = lsum[mt];
        l += __shfl_xor(l, 16, 64);
        l += __shfl_xor(l, 32, 64);
        l += pad_add;
        lf[mt] = l;
        if (q4 == 0) {
            int pq = sbase + (qoff + mt * 16 + ln15) * r;
            if (pq < TOK_L)
                lse5[(size_t)br * MHC + (size_t)(b * TOK_L + pq) * NH + hd] = __logf(l);
        }
    }

    bf16* od = (br == 0) ? oac : obr + (size_t)(br - 1) * HSZ;
    #pragma unroll
    for (int mt = 0; mt < 2; mt++) {
        #pragma unroll
        for (int g2 = 0; g2 < 4; g2++) {
            float l = __shfl(lf[mt], q4 * 4 + g2, 64);   // row sum for this D-row
            int row = mt * 16 + q4 * 4 + g2;
            int pq = sbase + (qoff + row) * r;
            if (pq >= TOK_L) continue;
            float linv = 1.f / l;
            #pragma unroll
            for (int dt = 0; dt < 4; dt++)
                od[(size_t)(b * TOK_L + pq) * EMB + hd * DH + dt * 16 + ln15] =
                    (bf16)(o[mt][dt][g2] * linv);
        }
    }
}

// ---------------------------------------------------------------------------
// LSE-softmax recombination of the 5 branches -> hn (bf16, next GEMM's A).
// 2 consecutive elements per thread; 4B/lane loads+stores.
// ---------------------------------------------------------------------------
__global__ __launch_bounds__(256) void attn_combine(
    const bf16* __restrict__ oac, const bf16* __restrict__ obr,
    const float* __restrict__ lse5, bf16* __restrict__ outb)
{
    size_t e = ((size_t)blockIdx.x * 256 + threadIdx.x) * 2;
    if (e >= HSZ) return;
    size_t g = e >> 6;                       // e even -> e, e+1 share group
    int h = (int)(g % NH);
    int p = (int)((g / NH) % TOK_L);
    float l0 = lse5[g];
    float m = l0;
    float lv[4];
    bool cov[4];
    #pragma unroll
    for (int j = 0; j < 4; j++) {
        int r = 2 << j;
        int gsz = (NH + r - 1) / r;
        cov[j] = ((p & (r - 1)) == (h / gsz));
        if (cov[j]) {
            lv[j] = lse5[(size_t)(j + 1) * MHC + g];
            m = fmaxf(m, lv[j]);
        }
    }
    float w0 = __expf(l0 - m);
    float wsum = w0;
    v2bf a0 = *(const v2bf*)(oac + e);
    float acc0 = w0 * (float)a0[0];
    float acc1 = w0 * (float)a0[1];
    #pragma unroll
    for (int j = 0; j < 4; j++) {
        if (cov[j]) {
            float wj = __expf(lv[j] - m);
            wsum += wj;
            v2bf aj = *(const v2bf*)(obr + (size_t)j * HSZ + e);
            acc0 = fmaf(wj, (float)aj[0], acc0);
            acc1 = fmaf(wj, (float)aj[1], acc1);
        }
    }
    float inv = 1.f / wsum;
    v2bf o2; o2[0] = (bf16)(acc0 * inv); o2[1] = (bf16)(acc1 * inv);
    *(v2bf*)(outb + e) = o2;
}

// out[b,c] = hn[b,0,:] @ head_w + head_b   (hn bf16, head fp32)
__global__ __launch_bounds__(256) void head_kernel(
    const bf16* __restrict__ hn, const float* __restrict__ hw,
    const float* __restrict__ hb, float* __restrict__ out)
{
    int b = blockIdx.y;
    int c = blockIdx.x * 256 + threadIdx.x;
    __shared__ float srow[EMB];
    for (int e = threadIdx.x; e < EMB; e += 256)
        srow[e] = (float)hn[(size_t)b * TOK_L * EMB + e];
    __syncthreads();
    if (c < 1000) {
        float acc = hb[c];
        for (int e = 0; e < EMB; e++)
            acc = fmaf(srow[e], hw[(size_t)e * 1000 + c], acc);
        out[b * 1000 + c] = acc;
    }
}

// ---------------------------------------------------------------------------
extern "C" void kernel_launch(void* const* d_in, const int* in_sizes, int n_in,
                              void* d_out, int out_size, void* d_ws, size_t ws_size,
                              hipStream_t stream)
{
    const float* x       = (const float*)d_in[0];
    const float* patch_w = (const float*)d_in[1];
    const float* patch_b = (const float*)d_in[2];
    const float* cls_tok = (const float*)d_in[3];
    const float* pos_emb = (const float*)d_in[4];
    const float* ln1_g   = (const float*)d_in[5];
    const float* ln1_b   = (const float*)d_in[6];
    const float* wq      = (const float*)d_in[7];
    const float* bq      = (const float*)d_in[8];
    const float* wk      = (const float*)d_in[9];
    const float* bk      = (const float*)d_in[10];
    const float* wv      = (const float*)d_in[11];
    const float* bv      = (const float*)d_in[12];
    const float* wo      = (const float*)d_in[13];
    const float* bo      = (const float*)d_in[14];
    const float* ln2_g   = (const float*)d_in[15];
    const float* ln2_b   = (const float*)d_in[16];
    const float* w1      = (const float*)d_in[17];
    const float* b1      = (const float*)d_in[18];
    const float* w2      = (const float*)d_in[19];
    const float* b2      = (const float*)d_in[20];
    const float* normf_g = (const float*)d_in[21];
    const float* normf_b = (const float*)d_in[22];
    const float* head_w  = (const float*)d_in[23];
    const float* head_b  = (const float*)d_in[24];
    float* out = (float*)d_out;

    char* wp = (char*)d_ws;
    auto alloc = [&](size_t bytes) { char* r = wp; wp += (bytes + 255) & ~(size_t)255; return r; };
    float* h    = (float*)alloc(HSZ * 4);
    bf16*  hn   = (bf16*)alloc(HSZ * 2);
    bf16*  QKV  = (bf16*)alloc((size_t)BATCH * TOK_L * QKVS * 2);
    bf16*  oac  = (bf16*)alloc(HSZ * 2);
    float* lse5 = (float*)alloc(5 * MHC * 4);
    bf16*  Vt   = (bf16*)alloc((size_t)12 * 24 * 64 * 768 * 2);
    bf16*  mid  = (bf16*)alloc(4 * HSZ * 2);       // FFN mid / Xp / obr overlay
    bf16*  obr  = mid;
    bf16*  Xp   = mid;

    bf16*  qkv_t0 = (bf16*)alloc((size_t)2 * QKVS * 768 * 2);
    bf16*  wo_t0  = (bf16*)alloc((size_t)2 * 768 * 768 * 2);
    bf16*  w1_t   = (bf16*)alloc((size_t)2 * 3072 * 768 * 2);
    bf16*  w2_t   = (bf16*)alloc((size_t)2 * 768 * 3072 * 2);
    bf16*  pw_b   = (bf16*)alloc((size_t)768 * 1024 * 2);
    float* bqkv   = (float*)alloc((size_t)2 * QKVS * 4);

    const int M = BATCH * TOK_L;        // 6146
    const int MT = (M + 127) / 128;     // 49

    prep_weights<<<dim3(14592), 256, 0, stream>>>(wq, wk, wv, wo, w1, w2, patch_w,
                                                  qkv_t0, wo_t0, w1_t, w2_t, pw_b);
    prep_small<<<dim3(18), 256, 0, stream>>>(bq, bk, bv, bqkv, cls_tok, pos_emb, h);

    gather_patches<<<dim3(BATCH * 3072), 256, 0, stream>>>(x, Xp);
    gemm_bf16<64><<<dim3(12, 48), 256, 0, stream>>>(Xp, pw_b, patch_b, h, nullptr,
                                                    BATCH * 3072, 768, 1024, 4, pos_emb, 8);

    for (int layer = 0; layer < 2; layer++) {
        size_t bOff  = (size_t)layer * 768;
        size_t b1Off = (size_t)layer * 3072;
        bf16* qt   = qkv_t0 + (size_t)layer * QKVS * 768;
        bf16* wo_t = wo_t0 + (size_t)layer * 589824;

        layernorm_kernel<<<dim3(M), 256, 0, stream>>>(h, ln1_g + bOff, ln1_b + bOff, hn, M);
        gemm_bf16<64><<<dim3(36, MT), 256, 0, stream>>>(hn, qt, bqkv + (size_t)layer * QKVS,
                                                        nullptr, QKV, M, QKVS, 768, 8, nullptr, 8);

        pack_vt<<<dim3(12, 12, 24), 256, 0, stream>>>(QKV, Vt);
        attn_mfma<<<dim3(1728), 256, 0, stream>>>(QKV, Vt, oac, obr, lse5);
        attn_combine<<<dim3((unsigned)((HSZ / 2 + 255) / 256)), 256, 0, stream>>>(oac, obr, lse5, hn);

        gemm_bf16<64><<<dim3(12, MT), 256, 0, stream>>>(hn, wo_t, bo + bOff, h, nullptr,
                                                        M, 768, 768, 1, nullptr, 8);

        layernorm_kernel<<<dim3(M), 256, 0, stream>>>(h, ln2_g + bOff, ln2_b + bOff, hn, M);
        gemm_bf16<128><<<dim3(24, MT), 256, 0, stream>>>(hn, w1_t + (size_t)layer * 2359296, b1 + b1Off,
                                                         nullptr, mid, M, 3072, 768, 8 | 2, nullptr, 8);
        gemm_bf16<64><<<dim3(12, MT), 256, 0, stream>>>(mid, w2_t + (size_t)layer * 2359296, b2 + bOff,
                                                        h, nullptr, M, 768, 3072, 1, nullptr, 4);
    }

    layernorm_kernel<<<dim3(M), 256, 0, stream>>>(h, normf_g, normf_b, hn, M);
    head_kernel<<<dim3(4, BATCH), 256, 0, stream>>>(hn, head_w, head_b, out);
}

// Round 15
// 924.584 us; speedup vs baseline: 1.0996x; 1.0022x over previous
//
#include <hip/hip_runtime.h>
#include <math.h>

#define TOK_L 3073
#define EMB 768
#define NH 12
#define DH 64
#define BATCH 2
#define QKVS 2304
#define HSZ ((size_t)BATCH * TOK_L * EMB)   // 4,720,128
#define MHC ((size_t)BATCH * TOK_L * NH)    // 73,752

typedef __bf16 bf16;
typedef __bf16 v8bf __attribute__((ext_vector_type(8)));
typedef __bf16 v4bf __attribute__((ext_vector_type(4)));
typedef __bf16 v2bf __attribute__((ext_vector_type(2)));
typedef float  v4f  __attribute__((ext_vector_type(4)));
typedef unsigned int v4u __attribute__((ext_vector_type(4)));

__device__ __forceinline__ v8bf zero8() {
    v8bf v;
    #pragma unroll
    for (int i = 0; i < 8; i++) v[i] = (bf16)0.f;
    return v;
}
__device__ __forceinline__ v4f zero4() {
    v4f v; v[0] = 0.f; v[1] = 0.f; v[2] = 0.f; v[3] = 0.f; return v;
}
__device__ __forceinline__ float gelu_f(float x) {
    return 0.5f * x * (1.0f + erff(x * 0.70710678118654752f));
}
// async global->LDS, 16B per lane; lds base must be wave-uniform (lane scatters +lane*16B)
__device__ __forceinline__ void gload16(const bf16* g, bf16* l) {
    __builtin_amdgcn_global_load_lds(
        (const __attribute__((address_space(1))) void*)g,
        (__attribute__((address_space(3))) void*)l, 16, 0, 0);
}

// ---------------------------------------------------------------------------
// Mega weight-prep: 12 transpose-converts + patch_w cvt. grid = 14592.
// ---------------------------------------------------------------------------
__device__ __forceinline__ void convT_tile(const float* __restrict__ src,
                                           bf16* __restrict__ dst,
                                           int K, int N, int tx, int ty)
{
    __shared__ float t[32][33];
    int n0 = tx * 32, k0 = ty * 32;
    int r = threadIdx.x >> 3, c4 = (threadIdx.x & 7) * 4;
    float4 v = *(const float4*)(src + (size_t)(k0 + r) * N + n0 + c4);
    t[r][c4 + 0] = v.x; t[r][c4 + 1] = v.y; t[r][c4 + 2] = v.z; t[r][c4 + 3] = v.w;
    __syncthreads();
    v4bf o;
    o[0] = (bf16)t[c4 + 0][r]; o[1] = (bf16)t[c4 + 1][r];
    o[2] = (bf16)t[c4 + 2][r]; o[3] = (bf16)t[c4 + 3][r];
    *(v4bf*)(dst + (size_t)(n0 + r) * K + k0 + c4) = o;
}

__global__ __launch_bounds__(256) void prep_weights(
    const float* __restrict__ wq, const float* __restrict__ wk,
    const float* __restrict__ wv, const float* __restrict__ wo,
    const float* __restrict__ w1, const float* __restrict__ w2,
    const float* __restrict__ patch_w,
    bf16* __restrict__ qkv_t0, bf16* __restrict__ wo_t0,
    bf16* __restrict__ w1_t, bf16* __restrict__ w2_t, bf16* __restrict__ pw_b)
{
    int bid = blockIdx.x;
    if (bid >= 13824) {
        int i = ((bid - 13824) * 256 + threadIdx.x) * 4;
        float4 v = *(const float4*)(patch_w + i);
        v4bf o; o[0] = (bf16)v.x; o[1] = (bf16)v.y; o[2] = (bf16)v.z; o[3] = (bf16)v.w;
        *(v4bf*)(pw_b + i) = o;
        return;
    }
    int layer = bid / 6912, t = bid % 6912;
    if (t < 1728) {
        int m = t / 576, tt = t % 576;
        const float* src = (m == 0 ? wq : m == 1 ? wk : wv) + (size_t)layer * 589824;
        bf16* dst = qkv_t0 + (size_t)layer * QKVS * 768 + (size_t)m * 589824;
        convT_tile(src, dst, 768, 768, tt % 24, tt / 24);
    } else if (t < 2304) {
        int tt = t - 1728;
        convT_tile(wo + (size_t)layer * 589824, wo_t0 + (size_t)layer * 589824,
                   768, 768, tt % 24, tt / 24);
    } else if (t < 4608) {
        int tt = t - 2304;
        convT_tile(w1 + (size_t)layer * 2359296, w1_t + (size_t)layer * 2359296,
                   768, 3072, tt % 96, tt / 96);
    } else {
        int tt = t - 4608;
        convT_tile(w2 + (size_t)layer * 2359296, w2_t + (size_t)layer * 2359296,
                   3072, 768, tt % 24, tt / 24);
    }
}

// concat q/k/v biases -> bqkv[layer][2304]; also init cls rows of h. grid 18.
__global__ __launch_bounds__(256) void prep_small(const float* __restrict__ bq,
    const float* __restrict__ bk, const float* __restrict__ bv, float* __restrict__ d,
    const float* __restrict__ cls, const float* __restrict__ pos, float* __restrict__ h)
{
    int i = blockIdx.x * 256 + threadIdx.x;
    if (i < 2 * QKVS) {
        int layer = i / QKVS, j = i % QKVS;
        const float* s = (j < 768) ? bq : (j < 1536) ? bk : bv;
        d[i] = s[(size_t)layer * 768 + (j & 767)];
    }
    if (i < 2 * 768) {
        int b = i / 768, e = i % 768;
        h[(size_t)b * TOK_L * EMB + e] = cls[e] + pos[e];
    }
}

// ---------------------------------------------------------------------------
// Patch gather: x (B,1,48,256,256) fp32 -> Xp (B*3072, 1024) bf16.
// float4 loads (16B/lane) + v4bf stores; 1024 = 256 threads x 4 exactly.
// ---------------------------------------------------------------------------
__global__ __launch_bounds__(256) void gather_patches(const float* __restrict__ x,
                                                      bf16* __restrict__ Xp) {
    int p = blockIdx.x;
    int b = p / 3072, pp = p % 3072;
    int px = pp >> 8, py = (pp >> 4) & 15, pz = pp & 15;
    int k = threadIdx.x * 4;                 // pw 4-aligned, contiguous quad
    int pd = k >> 8, ph = (k >> 4) & 15, pw = k & 15;
    size_t src = ((size_t)(b * 48 + px * 4 + pd)) * 65536
               + (size_t)(py * 16 + ph) * 256 + (size_t)(pz * 16 + pw);
    float4 v = *(const float4*)(x + src);
    v4bf o; o[0] = (bf16)v.x; o[1] = (bf16)v.y; o[2] = (bf16)v.z; o[3] = (bf16)v.w;
    *(v4bf*)(Xp + (size_t)p * 1024 + k) = o;
}

// ---------------------------------------------------------------------------
// XCD-chunked, panel-grouped tile remap (bijective, m204-style 8-way split).
// ---------------------------------------------------------------------------
__device__ __forceinline__ void remap_tile(int NX, int MY, int G, int& xo, int& yo)
{
    int id = blockIdx.x + NX * blockIdx.y;   // physical linear id
    int nwg = NX * MY;
    int xcd = id & 7, j = id >> 3;           // physical XCD + slot (id%8 = XCD)
    int q = nwg >> 3, r = nwg & 7;
    int n = xcd * q + (xcd < r ? xcd : r) + j;   // logical rank (bijective)
    int full = MY / G;
    int bpg = NX * G;
    int nf = full * bpg;
    if (n < nf) {
        int gi = n / bpg, w = n - gi * bpg;
        int xi = w / G;
        xo = xi; yo = gi * G + (w - xi * G);
    } else {
        int t = MY - full * G;               // tail rows (>0 iff taken)
        int w = n - nf;
        int xi = w / t;
        xo = xi; yo = full * G + (w - xi * t);
    }
}

// ---------------------------------------------------------------------------
// bf16 MFMA GEMM: 128xBN tile (BN=128 or 64), BK=32, global_load_lds staging.
// 3-buffer, prefetch-depth-2 pipeline with counted vmcnt (session-best).
// BN=64 sustains a higher staging rate than BN=128 in this structure
// (measured cross-shape R10/R13/R14: QKV BN=128->64 was -12% dispatch time),
// so QKV runs BN=64; FFN-up stays BN=128 (wash by the same arithmetic).
// gemm256 8-phase permanently reverted (3 ports falsified).
// flags: 1 acc into Cf, 2 gelu, 4 patch row remap (+pos fuse), 8 bf16 out
// ---------------------------------------------------------------------------
template<int BN>
__global__ __launch_bounds__(256) void gemm_bf16(
    const bf16* __restrict__ A, const bf16* __restrict__ Bt,
    const float* __restrict__ bias, float* __restrict__ Cf,
    bf16* __restrict__ Cb, int M, int N, int K, int flags,
    const float* __restrict__ pos, int G)
{
    __shared__ bf16 As[3][128 * 32];
    __shared__ bf16 Bs[3][BN * 32];
    const int tid = threadIdx.x;
    const int lane = tid & 63, wid = tid >> 6;
    const int ln15 = lane & 15, q4 = lane >> 4;
    int xo, yo;
    remap_tile(gridDim.x, gridDim.y, G, xo, yo);
    const int m0 = yo * 128, n0 = xo * BN;
    const int wm = (wid & 1) * 64, wn = (wid >> 1) * (BN / 2);
    const int srow = lane >> 2;
    const int schunk = (lane & 3) * 8;
    const int NF = BN / 32;

    v4f acc[4][NF];
    #pragma unroll
    for (int i = 0; i < 4; i++)
        #pragma unroll
        for (int j = 0; j < NF; j++) acc[i][j] = zero4();

    const int NT = K >> 5;
    auto stage = [&](int kt, int bi) {
        const int k0 = kt << 5;
        #pragma unroll
        for (int i = 0; i < 2; i++) {
            int rg = wid * 32 + i * 16;
            int gm = m0 + rg + srow; if (gm >= M) gm = M - 1;
            gload16(A + (size_t)gm * K + k0 + schunk, &As[bi][rg * 32]);
        }
        if (BN == 128) {
            #pragma unroll
            for (int i = 0; i < 2; i++) {
                int rg = wid * 32 + i * 16;
                gload16(Bt + (size_t)(n0 + rg + srow) * K + k0 + schunk, &Bs[bi][rg * 32]);
            }
        } else {
            int rg = wid * 16;
            gload16(Bt + (size_t)(n0 + rg + srow) * K + k0 + schunk, &Bs[bi][rg * 32]);
        }
    };

    stage(0, 0);
    if (NT > 1) stage(1, 1);

    int cur = 0;
    for (int kt = 0; kt < NT; kt++) {
        int nx2 = cur + 2; if (nx2 >= 3) nx2 -= 3;
        if (kt + 2 < NT) {
            stage(kt + 2, nx2);
            if (BN == 128) asm volatile("s_waitcnt vmcnt(8)" ::: "memory");
            else           asm volatile("s_waitcnt vmcnt(6)" ::: "memory");
        } else if (kt + 1 < NT) {
            if (BN == 128) asm volatile("s_waitcnt vmcnt(4)" ::: "memory");
            else           asm volatile("s_waitcnt vmcnt(3)" ::: "memory");
        } else {
            asm volatile("s_waitcnt vmcnt(0)" ::: "memory");
        }
        __builtin_amdgcn_sched_barrier(0);
        __builtin_amdgcn_s_barrier();

        v8bf af[4], bfr[NF];
        #pragma unroll
        for (int mt = 0; mt < 4; mt++)
            af[mt] = *(const v8bf*)(&As[cur][(wm + mt * 16 + ln15) * 32 + q4 * 8]);
        #pragma unroll
        for (int nt = 0; nt < NF; nt++)
            bfr[nt] = *(const v8bf*)(&Bs[cur][(wn + nt * 16 + ln15) * 32 + q4 * 8]);
        #pragma unroll
        for (int mt = 0; mt < 4; mt++)
            #pragma unroll
            for (int nt = 0; nt < NF; nt++)
                acc[mt][nt] = __builtin_amdgcn_mfma_f32_16x16x32_bf16(af[mt], bfr[nt], acc[mt][nt], 0, 0, 0);
        __builtin_amdgcn_s_barrier();
        cur = cur + 1 == 3 ? 0 : cur + 1;
    }
    #pragma unroll
    for (int mt = 0; mt < 4; mt++) {
        #pragma unroll
        for (int nt = 0; nt < NF; nt++) {
            #pragma unroll
            for (int g = 0; g < 4; g++) {
                int row = m0 + wm + mt * 16 + q4 * 4 + g;
                if (row >= M) continue;
                int col = n0 + wn + nt * 16 + ln15;
                float v = acc[mt][nt][g] + bias[col];
                if (flags & 2) v = gelu_f(v);
                size_t crow;
                if (flags & 4) {
                    int rowp = row % 3072;
                    crow = (size_t)(row + row / 3072 + 1);
                    v += pos[(size_t)(rowp + 1) * EMB + col];
                } else crow = (size_t)row;
                size_t ci = crow * (size_t)N + col;
                if (flags & 8) Cb[ci] = (bf16)v;
                else { if (flags & 1) v += Cf[ci]; Cf[ci] = v; }
            }
        }
    }
}

// ---------------------------------------------------------------------------
// LayerNorm over last dim (768), fp32 in -> bf16 out. Wave shfl_xor
// reductions + one cross-wave LDS combine each (2 barriers/row).
// rstride: row = blockIdx.x * rstride (final LN only needs the 2 CLS rows:
// grid 2, rstride = TOK_L; head_kernel reads only rows 0 and TOK_L).
// ---------------------------------------------------------------------------
__global__ __launch_bounds__(256) void layernorm_kernel(
    const float* __restrict__ x, const float* __restrict__ g,
    const float* __restrict__ bb, bf16* __restrict__ y, int nrows, int rstride)
{
    int row = blockIdx.x * rstride;
    if (row >= nrows) return;
    int tid = threadIdx.x;
    int lane = tid & 63, wv = tid >> 6;
    const float* xr = x + (size_t)row * EMB;
    float v0 = xr[tid], v1 = xr[tid + 256], v2 = xr[tid + 512];
    __shared__ float ws[4], ws2[4];
    float s = v0 + v1 + v2;
    #pragma unroll
    for (int o = 1; o < 64; o <<= 1) s += __shfl_xor(s, o, 64);
    if (lane == 0) ws[wv] = s;
    __syncthreads();
    float mu = (ws[0] + ws[1] + ws[2] + ws[3]) * (1.f / 768.f);
    float d0 = v0 - mu, d1 = v1 - mu, d2 = v2 - mu;
    float q = d0 * d0 + d1 * d1 + d2 * d2;
    #pragma unroll
    for (int o = 1; o < 64; o <<= 1) q += __shfl_xor(q, o, 64);
    if (lane == 0) ws2[wv] = q;
    __syncthreads();
    float var = (ws2[0] + ws2[1] + ws2[2] + ws2[3]) * (1.f / 768.f);
    float rs = rsqrtf(var + 1e-5f);
    bf16* yr = y + (size_t)row * EMB;
    yr[tid]       = (bf16)(d0 * rs * g[tid]       + bb[tid]);
    yr[tid + 256] = (bf16)(d1 * rs * g[tid + 256] + bb[tid + 256]);
    yr[tid + 512] = (bf16)(d2 * rs * g[tid + 512] + bb[tid + 512]);
}

// ---------------------------------------------------------------------------
// Pack V transposed per branch-slot: Vt[yy][b*NH+h][dh 64][key 768] bf16.
// ---------------------------------------------------------------------------
__global__ __launch_bounds__(256) void pack_vt(const bf16* __restrict__ qkv,
                                               bf16* __restrict__ Vt)
{
    __shared__ bf16 t[64 * 65];
    int yy = blockIdx.y;
    int br, seg;
    if (yy < 5)       { br = 0; seg = yy; }
    else if (yy < 8)  { br = 1; seg = yy - 5; }
    else if (yy < 10) { br = 2; seg = yy - 8; }
    else if (yy == 10){ br = 3; seg = 0; }
    else              { br = 4; seg = 0; }
    const int r = 1 << br, w = 768 << br;
    const int gsz = (NH + r - 1) / r;
    const int bh = blockIdx.z;
    const int b = bh / NH, hd = bh % NH;
    const int off = hd / gsz;
    const int kbase = seg * w + off;
    const int kt = blockIdx.x;
    const int tid = threadIdx.x;
    const int dq = (tid & 7) * 8;
    #pragma unroll
    for (int p = 0; p < 2; p++) {
        int jl = (tid >> 3) + p * 32;
        int pk = kbase + (kt * 64 + jl) * r;
        v8bf val = (pk < TOK_L)
            ? *(const v8bf*)(qkv + (size_t)(b * TOK_L + pk) * QKVS + 1536 + hd * DH + dq)
            : zero8();
        #pragma unroll
        for (int i = 0; i < 8; i++) t[jl * 65 + dq + i] = val[i];
    }
    __syncthreads();
    #pragma unroll
    for (int p = 0; p < 2; p++) {
        int d = (tid >> 3) + p * 32;
        int kk = (tid & 7) * 8;
        v8bf o;
        #pragma unroll
        for (int i = 0; i < 8; i++) o[i] = t[(kk + i) * 65 + d];
        *(v8bf*)(Vt + ((size_t)(yy * 24 + bh) * 64 + d) * 768 + kt * 64 + kk) = o;
    }
}

// ---------------------------------------------------------------------------
// MFMA dilated attention, in-register softmax (swapped QK^T + cvt_pk +
// permlane swaps). K tiles staged via async global_load_lds, double-buffered,
// XOR-swizzled (pre-swizzled global source, swizzled read).
// Padded keys: p masked to 0; (768 - n_valid) added to denominator.
// ---------------------------------------------------------------------------
__global__ __launch_bounds__(256) void attn_mfma(
    const bf16* __restrict__ qkv, const bf16* __restrict__ Vt,
    bf16* __restrict__ oac, bf16* __restrict__ obr, float* __restrict__ lse5)
{
    __shared__ bf16 kl[2 * 4096];        // [2][64 keys][64 dh], 16B-slot swizzled
    const int tid = threadIdx.x;
    const int lane = tid & 63, wid = tid >> 6;
    const int ln15 = lane & 15, q4 = lane >> 4;
    const int bid = blockIdx.x;
    const int xcd = bid & 7, rest = bid >> 3;
    const int slot = rest / 6, t = rest - slot * 6;
    const int g = (slot << 3) | xcd;          // 0..287
    const int yy = g / 24, bh = g - yy * 24;
    int br, seg;
    if (yy < 5)       { br = 0; seg = yy; }
    else if (yy < 8)  { br = 1; seg = yy - 5; }
    else if (yy < 10) { br = 2; seg = yy - 8; }
    else if (yy == 10){ br = 3; seg = 0; }
    else              { br = 4; seg = 0; }
    const int r = 1 << br, w = 768 << br;
    const int gsz = (NH + r - 1) / r;
    const int b = bh / NH, hd = bh % NH;
    const int off = hd / gsz;
    const int sbase = seg * w + off;
    if (sbase + (t * 128) * r >= TOK_L) return;     // block-uniform early exit

    int n_valid = (TOK_L - sbase + r - 1) / r;
    if (n_valid > 768) n_valid = 768;
    const int kt_lim = (n_valid + 63) >> 6;
    const float pad_add = (float)(768 - n_valid);
    const int qoff = t * 128 + wid * 32;
    const bool wactive = (sbase + qoff * r) < TOK_L;

    const bf16* qb_ = qkv + hd * DH;
    const bf16* kb_ = qkv + 768 + hd * DH;

    // read-side XOR swizzle key (elements, 8-elem = 16B granules)
    const int swz = (ln15 & 7) * 8;

    auto stageK = [&](int ktv, int bufi) {
        #pragma unroll
        for (int p = 0; p < 2; p++) {
            int row = (tid >> 3) + p * 32;
            int pk = sbase + (ktv * 64 + row) * r;
            if (pk >= TOK_L) pk = 0;                // garbage row; masked later
            int colsw = ((tid & 7) ^ ((tid >> 3) & 7)) * 8;   // pre-swizzled source
            gload16(kb_ + (size_t)(b * TOK_L + pk) * QKVS + colsw,
                    kl + bufi * 4096 + wid * 512 + p * 2048);
        }
    };

    // Q fragments, pre-scaled by Dh^-0.5 = 0.125 (exact in bf16)
    v8bf qf[2][2];
    #pragma unroll
    for (int mt = 0; mt < 2; mt++) {
        int pq = sbase + (qoff + mt * 16 + ln15) * r;
        #pragma unroll
        for (int ks = 0; ks < 2; ks++) {
            v8bf qv = (pq < TOK_L)
                ? *(const v8bf*)(qb_ + (size_t)(b * TOK_L + pq) * QKVS + ks * 32 + q4 * 8)
                : zero8();
            #pragma unroll
            for (int i = 0; i < 8; i++) qv[i] = (bf16)((float)qv[i] * 0.125f);
            qf[mt][ks] = qv;
        }
    }
    v4f o[2][4];
    float lsum[2];
    #pragma unroll
    for (int mt = 0; mt < 2; mt++) {
        lsum[mt] = 0.f;
        #pragma unroll
        for (int dt = 0; dt < 4; dt++) o[mt][dt] = zero4();
    }

    const bf16* vtb = Vt + (size_t)(yy * 24 + bh) * 64 * 768;

    stageK(0, 0);
    __syncthreads();

    for (int kt = 0; kt < kt_lim; kt++) {
        const int cur = kt & 1;
        if (kt + 1 < kt_lim) stageK(kt + 1, cur ^ 1);
        if (wactive) {
            const bf16* klc = kl + cur * 4096;
            v8bf kf[4][2];
            #pragma unroll
            for (int nt = 0; nt < 4; nt++)
                #pragma unroll
                for (int ks = 0; ks < 2; ks++)
                    kf[nt][ks] = *(const v8bf*)(klc + (nt * 16 + ln15) * 64
                                                + ((ks * 32 + q4 * 8) ^ swz));
            // paw[mt][ks][4 words] = PV A-fragment, built fully in-register
            unsigned int paw[2][2][4];
            #pragma unroll
            for (int mt = 0; mt < 2; mt++) {
                // swapped QK^T: S^T[k][q], lane ln15 = q, (q4, reg) = k
                v4f s[4];
                #pragma unroll
                for (int nt = 0; nt < 4; nt++) {
                    s[nt] = __builtin_amdgcn_mfma_f32_16x16x32_bf16(kf[nt][0], qf[mt][0], zero4(), 0, 0, 0);
                    s[nt] = __builtin_amdgcn_mfma_f32_16x16x32_bf16(kf[nt][1], qf[mt][1], s[nt], 0, 0, 0);
                }
                unsigned int W[4][2];
                float ls = 0.f;
                #pragma unroll
                for (int nt = 0; nt < 4; nt++) {
                    int kb = kt * 64 + nt * 16 + q4 * 4;
                    float p0 = (kb + 0 < n_valid) ? __expf(s[nt][0]) : 0.f;
                    float p1 = (kb + 1 < n_valid) ? __expf(s[nt][1]) : 0.f;
                    float p2 = (kb + 2 < n_valid) ? __expf(s[nt][2]) : 0.f;
                    float p3 = (kb + 3 < n_valid) ? __expf(s[nt][3]) : 0.f;
                    ls += (p0 + p1) + (p2 + p3);
                    asm("v_cvt_pk_bf16_f32 %0, %1, %2" : "=v"(W[nt][0]) : "v"(p0), "v"(p1));
                    asm("v_cvt_pk_bf16_f32 %0, %1, %2" : "=v"(W[nt][1]) : "v"(p2), "v"(p3));
                }
                lsum[mt] += ls;
                // quarter-lane regroup: perm32 then perm16 delivers, per target
                // quarter tq4, the words of source lane ln15+16*q4' with
                // nt = 2ks + (tq4>>1), q4' = 2*(tq4&1) (+1 for the late pair).
                #pragma unroll
                for (int ks = 0; ks < 2; ks++) {
                    #pragma unroll
                    for (int h = 0; h < 2; h++) {
                        unsigned int a = W[2 * ks][h], c = W[2 * ks + 1][h];
                        asm("v_permlane32_swap_b32 %0, %1" : "+v"(a), "+v"(c));
                        asm("v_permlane16_swap_b32 %0, %1" : "+v"(a), "+v"(c));
                        paw[mt][ks][h]     = a;   // E_h
                        paw[mt][ks][2 + h] = c;   // L_h
                    }
                }
            }
            #pragma unroll
            for (int ks = 0; ks < 2; ks++) {
                v8bf vf[4];
                #pragma unroll
                for (int dt = 0; dt < 4; dt++)
                    vf[dt] = *(const v8bf*)(vtb + (size_t)(dt * 16 + ln15) * 768 + kt * 64 + ks * 32 + q4 * 8);
                #pragma unroll
                for (int mt = 0; mt < 2; mt++) {
                    v4u pw = { paw[mt][ks][0], paw[mt][ks][1], paw[mt][ks][2], paw[mt][ks][3] };
                    v8bf pa = __builtin_bit_cast(v8bf, pw);
                    #pragma unroll
                    for (int dt = 0; dt < 4; dt++)
                        o[mt][dt] = __builtin_amdgcn_mfma_f32_16x16x32_bf16(pa, vf[dt], o[mt][dt], 0, 0, 0);
                }
            }
        }
        __syncthreads();
    }
    if (!wactive) return;

    // row sums: lane holds partial for q = mt*16+ln15; reduce across quarters
    float lf[2];
    #pragma unroll
    for (int mt = 0; mt < 2; mt++) {
        float l = lsum[mt];
        l += __shfl_xor(l, 16, 64);
        l += __shfl_xor(l, 32, 64);
        l += pad_add;
        lf[mt] = l;
        if (q4 == 0) {
            int pq = sbase + (qoff + mt * 16 + ln15) * r;
            if (pq < TOK_L)
                lse5[(size_t)br * MHC + (size_t)(b * TOK_L + pq) * NH + hd] = __logf(l);
        }
    }

    bf16* od = (br == 0) ? oac : obr + (size_t)(br - 1) * HSZ;
    #pragma unroll
    for (int mt = 0; mt < 2; mt++) {
        #pragma unroll
        for (int g2 = 0; g2 < 4; g2++) {
            float l = __shfl(lf[mt], q4 * 4 + g2, 64);   // row sum for this D-row
            int row = mt * 16 + q4 * 4 + g2;
            int pq = sbase + (qoff + row) * r;
            if (pq >= TOK_L) continue;
            float linv = 1.f / l;
            #pragma unroll
            for (int dt = 0; dt < 4; dt++)
                od[(size_t)(b * TOK_L + pq) * EMB + hd * DH + dt * 16 + ln15] =
                    (bf16)(o[mt][dt][g2] * linv);
        }
    }
}

// ---------------------------------------------------------------------------
// LSE-softmax recombination of the 5 branches -> hn (bf16, next GEMM's A).
// 2 consecutive elements per thread; 4B/lane loads+stores.
// ---------------------------------------------------------------------------
__global__ __launch_bounds__(256) void attn_combine(
    const bf16* __restrict__ oac, const bf16* __restrict__ obr,
    const float* __restrict__ lse5, bf16* __restrict__ outb)
{
    size_t e = ((size_t)blockIdx.x * 256 + threadIdx.x) * 2;
    if (e >= HSZ) return;
    size_t g = e >> 6;                       // e even -> e, e+1 share group
    int h = (int)(g % NH);
    int p = (int)((g / NH) % TOK_L);
    float l0 = lse5[g];
    float m = l0;
    float lv[4];
    bool cov[4];
    #pragma unroll
    for (int j = 0; j < 4; j++) {
        int r = 2 << j;
        int gsz = (NH + r - 1) / r;
        cov[j] = ((p & (r - 1)) == (h / gsz));
        if (cov[j]) {
            lv[j] = lse5[(size_t)(j + 1) * MHC + g];
            m = fmaxf(m, lv[j]);
        }
    }
    float w0 = __expf(l0 - m);
    float wsum = w0;
    v2bf a0 = *(const v2bf*)(oac + e);
    float acc0 = w0 * (float)a0[0];
    float acc1 = w0 * (float)a0[1];
    #pragma unroll
    for (int j = 0; j < 4; j++) {
        if (cov[j]) {
            float wj = __expf(lv[j] - m);
            wsum += wj;
            v2bf aj = *(const v2bf*)(obr + (size_t)j * HSZ + e);
            acc0 = fmaf(wj, (float)aj[0], acc0);
            acc1 = fmaf(wj, (float)aj[1], acc1);
        }
    }
    float inv = 1.f / wsum;
    v2bf o2; o2[0] = (bf16)(acc0 * inv); o2[1] = (bf16)(acc1 * inv);
    *(v2bf*)(outb + e) = o2;
}

// out[b,c] = hn[b,0,:] @ head_w + head_b   (hn bf16, head fp32)
__global__ __launch_bounds__(256) void head_kernel(
    const bf16* __restrict__ hn, const float* __restrict__ hw,
    const float* __restrict__ hb, float* __restrict__ out)
{
    int b = blockIdx.y;
    int c = blockIdx.x * 256 + threadIdx.x;
    __shared__ float srow[EMB];
    for (int e = threadIdx.x; e < EMB; e += 256)
        srow[e] = (float)hn[(size_t)b * TOK_L * EMB + e];
    __syncthreads();
    if (c < 1000) {
        float acc = hb[c];
        for (int e = 0; e < EMB; e++)
            acc = fmaf(srow[e], hw[(size_t)e * 1000 + c], acc);
        out[b * 1000 + c] = acc;
    }
}

// ---------------------------------------------------------------------------
extern "C" void kernel_launch(void* const* d_in, const int* in_sizes, int n_in,
                              void* d_out, int out_size, void* d_ws, size_t ws_size,
                              hipStream_t stream)
{
    const float* x       = (const float*)d_in[0];
    const float* patch_w = (const float*)d_in[1];
    const float* patch_b = (const float*)d_in[2];
    const float* cls_tok = (const float*)d_in[3];
    const float* pos_emb = (const float*)d_in[4];
    const float* ln1_g   = (const float*)d_in[5];
    const float* ln1_b   = (const float*)d_in[6];
    const float* wq      = (const float*)d_in[7];
    const float* bq      = (const float*)d_in[8];
    const float* wk      = (const float*)d_in[9];
    const float* bk      = (const float*)d_in[10];
    const float* wv      = (const float*)d_in[11];
    const float* bv      = (const float*)d_in[12];
    const float* wo      = (const float*)d_in[13];
    const float* bo      = (const float*)d_in[14];
    const float* ln2_g   = (const float*)d_in[15];
    const float* ln2_b   = (const float*)d_in[16];
    const float* w1      = (const float*)d_in[17];
    const float* b1      = (const float*)d_in[18];
    const float* w2      = (const float*)d_in[19];
    const float* b2      = (const float*)d_in[20];
    const float* normf_g = (const float*)d_in[21];
    const float* normf_b = (const float*)d_in[22];
    const float* head_w  = (const float*)d_in[23];
    const float* head_b  = (const float*)d_in[24];
    float* out = (float*)d_out;

    char* wp = (char*)d_ws;
    auto alloc = [&](size_t bytes) { char* r = wp; wp += (bytes + 255) & ~(size_t)255; return r; };
    float* h    = (float*)alloc(HSZ * 4);
    bf16*  hn   = (bf16*)alloc(HSZ * 2);
    bf16*  QKV  = (bf16*)alloc((size_t)BATCH * TOK_L * QKVS * 2);
    bf16*  oac  = (bf16*)alloc(HSZ * 2);
    float* lse5 = (float*)alloc(5 * MHC * 4);
    bf16*  Vt   = (bf16*)alloc((size_t)12 * 24 * 64 * 768 * 2);
    bf16*  mid  = (bf16*)alloc(4 * HSZ * 2);       // FFN mid / Xp / obr overlay
    bf16*  obr  = mid;
    bf16*  Xp   = mid;

    bf16*  qkv_t0 = (bf16*)alloc((size_t)2 * QKVS * 768 * 2);
    bf16*  wo_t0  = (bf16*)alloc((size_t)2 * 768 * 768 * 2);
    bf16*  w1_t   = (bf16*)alloc((size_t)2 * 3072 * 768 * 2);
    bf16*  w2_t   = (bf16*)alloc((size_t)2 * 768 * 3072 * 2);
    bf16*  pw_b   = (bf16*)alloc((size_t)768 * 1024 * 2);
    float* bqkv   = (float*)alloc((size_t)2 * QKVS * 4);

    const int M = BATCH * TOK_L;        // 6146
    const int MT = (M + 127) / 128;     // 49

    prep_weights<<<dim3(14592), 256, 0, stream>>>(wq, wk, wv, wo, w1, w2, patch_w,
                                                  qkv_t0, wo_t0, w1_t, w2_t, pw_b);
    prep_small<<<dim3(18), 256, 0, stream>>>(bq, bk, bv, bqkv, cls_tok, pos_emb, h);

    gather_patches<<<dim3(BATCH * 3072), 256, 0, stream>>>(x, Xp);
    gemm_bf16<64><<<dim3(12, 48), 256, 0, stream>>>(Xp, pw_b, patch_b, h, nullptr,
                                                    BATCH * 3072, 768, 1024, 4, pos_emb, 8);

    for (int layer = 0; layer < 2; layer++) {
        size_t bOff  = (size_t)layer * 768;
        size_t b1Off = (size_t)layer * 3072;
        bf16* qt   = qkv_t0 + (size_t)layer * QKVS * 768;
        bf16* wo_t = wo_t0 + (size_t)layer * 589824;

        layernorm_kernel<<<dim3(M), 256, 0, stream>>>(h, ln1_g + bOff, ln1_b + bOff, hn, M, 1);
        gemm_bf16<64><<<dim3(36, MT), 256, 0, stream>>>(hn, qt, bqkv + (size_t)layer * QKVS,
                                                        nullptr, QKV, M, QKVS, 768, 8, nullptr, 8);

        pack_vt<<<dim3(12, 12, 24), 256, 0, stream>>>(QKV, Vt);
        attn_mfma<<<dim3(1728), 256, 0, stream>>>(QKV, Vt, oac, obr, lse5);
        attn_combine<<<dim3((unsigned)((HSZ / 2 + 255) / 256)), 256, 0, stream>>>(oac, obr, lse5, hn);

        gemm_bf16<64><<<dim3(12, MT), 256, 0, stream>>>(hn, wo_t, bo + bOff, h, nullptr,
                                                        M, 768, 768, 1, nullptr, 8);

        layernorm_kernel<<<dim3(M), 256, 0, stream>>>(h, ln2_g + bOff, ln2_b + bOff, hn, M, 1);
        gemm_bf16<128><<<dim3(24, MT), 256, 0, stream>>>(hn, w1_t + (size_t)layer * 2359296, b1 + b1Off,
                                                         nullptr, mid, M, 3072, 768, 8 | 2, nullptr, 8);
        gemm_bf16<64><<<dim3(12, MT), 256, 0, stream>>>(mid, w2_t + (size_t)layer * 2359296, b2 + bOff,
                                                        h, nullptr, M, 768, 3072, 1, nullptr, 4);
    }

    // final LN: head consumes only the 2 CLS rows (0 and TOK_L) -> grid 2
    layernorm_kernel<<<dim3(BATCH), 256, 0, stream>>>(h, normf_g, normf_b, hn, M, TOK_L);
    head_kernel<<<dim3(4, BATCH), 256, 0, stream>>>(hn, head_w, head_b, out);
}